// Round 7
// baseline (3285.662 us; speedup 1.0000x reference)
//
#include <hip/hip_runtime.h>

#define NOBS 2048
#define NX   128
#define NY   64
#define BS   8            // scenarios per solver block (256 blocks, 1/CU, all resident)
#define NT   1024         // 16 waves
#define NWAVE (NT / 64)
#define NITER 64

typedef short short8 __attribute__((ext_vector_type(8)));   // 8 bf16 (4 VGPRs)
typedef float f32x4 __attribute__((ext_vector_type(4)));    // MFMA accumulator
typedef unsigned short u16x4 __attribute__((ext_vector_type(4)));

// ---- bf16 split helpers (RNE) ----
__device__ __forceinline__ unsigned short bf16_rne(float x) {
    unsigned u = __float_as_uint(x);
    return (unsigned short)((u + 0x7FFFu + ((u >> 16) & 1u)) >> 16);
}
__device__ __forceinline__ float bf16_tof(unsigned short h) {
    return __uint_as_float(((unsigned)h) << 16);
}

// ---- DPP wave reduction (prep only) ----
template <int CTRL>
__device__ __forceinline__ float dpp_f(float x) {
    return __int_as_float(__builtin_amdgcn_update_dpp(
        0, __float_as_int(x), CTRL, 0xf, 0xf, true));
}
__device__ __forceinline__ float wave_sum64(float v) {
    v += dpp_f<0x111>(v);
    v += dpp_f<0x112>(v);
    v += dpp_f<0x114>(v);
    v += dpp_f<0x118>(v);
    v += dpp_f<0x142>(v);
    v += dpp_f<0x143>(v);   // lane 63 = total
    return v;
}

// ---- Kernel 1: Y_hat = X@W^T + b ; epsum ; ep bf16 3-way split (two layouts) ----
// e = hi + md + lo + r, |r| <~ 2^-24 |e|.  epT uses (hi, md) [2-way], epA uses all 3.
__global__ __launch_bounds__(256) void prep_kernel(
    const float* __restrict__ X, const float* __restrict__ Y,
    const float* __restrict__ W, const float* __restrict__ b,
    float* __restrict__ yhat_out, float* __restrict__ epsum,
    unsigned short* __restrict__ epT_hi, unsigned short* __restrict__ epT_lo,
    unsigned short* __restrict__ epA_hi, unsigned short* __restrict__ epA_md,
    unsigned short* __restrict__ epA_lo)
{
    __shared__ float Xs[4][NX];
    const int t = threadIdx.x;
    const int row0 = blockIdx.x * 4;
    for (int f = t; f < 4 * NX; f += 256)
        Xs[f >> 7][f & 127] = X[(row0 + (f >> 7)) * NX + (f & 127)];
    __syncthreads();

    const int k = t & 63;
    const int r = t >> 6;
    const float4* W4 = reinterpret_cast<const float4*>(W + k * NX);
    const float4* X4 = reinterpret_cast<const float4*>(&Xs[r][0]);
    float acc = 0.f;
    #pragma unroll
    for (int x = 0; x < NX / 4; ++x) {
        float4 wv = W4[x];
        float4 xv = X4[x];
        acc += wv.x * xv.x + wv.y * xv.y + wv.z * xv.z + wv.w * xv.w;
    }
    const float yh = acc + b[k];
    const int i = row0 + r;
    yhat_out[i * NY + k] = yh;
    const float e = Y[i * NY + k] - yh;

    const unsigned short hi = bf16_rne(e);
    const float r1 = e - bf16_tof(hi);
    const unsigned short md = bf16_rne(r1);
    const unsigned short lo = bf16_rne(r1 - bf16_tof(md));
    // Phase C A-frag (rows = k, K = i):  A[row=lane&15][kk=8*(lane>>4)+d]
    {
        const int m  = k >> 4;
        const int q  = i >> 5;
        const int lc = (k & 15) + 16 * ((i >> 3) & 3);
        const int d  = i & 7;
        const int idx = ((m * 64 + q) * 64 + lc) * 8 + d;
        epT_hi[idx] = hi;
        epT_lo[idx] = md;
    }
    // Phase A A-frag (rows = i, K = k)
    {
        const int m  = i >> 4;
        const int q  = k >> 5;
        const int lc = (i & 15) + 16 * ((k >> 3) & 3);
        const int d  = k & 7;
        const int idx = ((m * 2 + q) * 64 + lc) * 8 + d;
        epA_hi[idx] = hi;
        epA_md[idx] = md;
        epA_lo[idx] = lo;
    }

    float se = wave_sum64(e);
    if ((t & 63) == 63) atomicAdd(epsum, se);
}

// ---- Kernel 2: batched projected-subgradient DRO solve ----
// Phase A on MFMA with 3-way bf16 split (6 terms, fp32-class error);
// Phase C on MFMA with 2-way split (3 terms, R5-proven); 5 barriers/iter.
__global__ __launch_bounds__(NT, 4) void solve_kernel(
    const float* __restrict__ yhat, const float* __restrict__ epsum,
    const float* __restrict__ rho_p,
    const unsigned short* __restrict__ epT_hi, const unsigned short* __restrict__ epT_lo,
    const unsigned short* __restrict__ epA_hi, const unsigned short* __restrict__ epA_md,
    const unsigned short* __restrict__ epA_lo,
    float* __restrict__ zout)
{
    __shared__ float Zs[BS][NY];                 // 2 KB
    __shared__ float Yh[BS][NY];                 // 2 KB
    __shared__ unsigned short VT_hi[BS][2056];   // 32.1 KB
    __shared__ unsigned short VT_lo[BS][2056];   // 32.1 KB
    __shared__ __align__(16) unsigned short Zb_hi[16][72];  // 2.25 KB (cols 8..15 dup)
    __shared__ __align__(16) unsigned short Zb_md[16][72];  // 2.25 KB
    __shared__ __align__(16) unsigned short Zb_lo[16][72];  // 2.25 KB
    __shared__ float Rp2[4][4][64][4];           // 16 KB  [g][m][lane][reg]
    __shared__ float redM[NWAVE][BS];            // per-wave umax partials
    __shared__ float red2[NWAVE][BS][4];         // per-wave {pa,pe,pas,pes}
    __shared__ float cS[16], lamS[16];           // cols 8..15 dup
    __shared__ __align__(16) unsigned short zb[8];

    const int t = threadIdx.x;
    const int lane = t & 63;
    const int wv = t >> 6;
    const int jb = lane & 15;      // MFMA column
    const int h  = lane >> 4;      // frag k-chunk / row-group
    const int j8 = jb & 7;         // actual scenario
    const bool hiHalf = (jb >= 8);
    const int sc0 = blockIdx.x * BS;
    const float rho = rho_p[0];

    if (t < BS * NY) {
        const int j = t >> 6, k = t & 63;
        Yh[j][k] = yhat[(sc0 + j) * NY + k];
        Zs[j][k] = 1.0f / 64.0f;
    }
    {   // z0 = 1/64 exact in bf16 (power of two) -> md = lo = 0
        const int j = t >> 6, k = t & 63;
        Zb_hi[j][k] = bf16_rne(1.0f / 64.0f);
        Zb_md[j][k] = 0;
        Zb_lo[j][k] = 0;
    }
    if (t < 16) {
        cS[t] = epsum[0] * (1.0f / 131072.0f);  // mean(ep) == mean(ep @ z0)
        lamS[t] = 1.0f;
    }
    if (t < 8) zb[t] = 0;
    __syncthreads();

    for (int it = 0; it < NITER; ++it) {
        const float lr = 0.05f / sqrtf((float)it + 1.0f);

        // ---- Phase A: S = ep.z - c via MFMA, 6-term 3-way split ----
        // wave wv owns i in [128wv, 128wv+128)
        f32x4 acc[8];
        #pragma unroll
        for (int mi = 0; mi < 8; ++mi) acc[mi] = (f32x4){0.f, 0.f, 0.f, 0.f};
        #pragma unroll
        for (int q = 0; q < 2; ++q) {
            const short8 zh = *(const short8*)&Zb_hi[jb][(q << 5) + (h << 3)];
            const short8 zm = *(const short8*)&Zb_md[jb][(q << 5) + (h << 3)];
            const short8 zl = *(const short8*)&Zb_lo[jb][(q << 5) + (h << 3)];
            #pragma unroll
            for (int mi = 0; mi < 8; ++mi) {
                const int aoff = ((((wv << 3) + mi) * 2 + q) * 64 + lane) * 8;
                const short8 ah = *(const short8*)(epA_hi + aoff);
                const short8 am = *(const short8*)(epA_md + aoff);
                const short8 al = *(const short8*)(epA_lo + aoff);
                acc[mi] = __builtin_amdgcn_mfma_f32_16x16x32_bf16(al, zh, acc[mi], 0, 0, 0); // lH
                acc[mi] = __builtin_amdgcn_mfma_f32_16x16x32_bf16(ah, zl, acc[mi], 0, 0, 0); // hL
                acc[mi] = __builtin_amdgcn_mfma_f32_16x16x32_bf16(am, zm, acc[mi], 0, 0, 0); // mM
                acc[mi] = __builtin_amdgcn_mfma_f32_16x16x32_bf16(am, zh, acc[mi], 0, 0, 0); // mH
                acc[mi] = __builtin_amdgcn_mfma_f32_16x16x32_bf16(ah, zm, acc[mi], 0, 0, 0); // hM
                acc[mi] = __builtin_amdgcn_mfma_f32_16x16x32_bf16(ah, zh, acc[mi], 0, 0, 0); // hH
            }
        }
        // lane-half split: jb<8 -> m-tiles 0..3, jb>=8 -> 4..7 (same scenario j8)
        const float cR = cS[jb];
        const float lm = lamS[jb];
        float sv_[4][4], u_[4][4];
        #pragma unroll
        for (int n = 0; n < 4; ++n)
            #pragma unroll
            for (int p = 0; p < 4; ++p) {
                const float av = hiHalf ? acc[n + 4][p] : acc[n][p];
                const float ss = av - cR;       // s for i = 16*(8wv + 4*hiHalf + n) + 4h + p
                sv_[n][p] = ss;
                u_[n][p] = ss * ss;
            }

        // ---- Phase B1: per-wave umax (in-lane 16 -> xor 8/16/32) ----
        float pm = u_[0][0];
        #pragma unroll
        for (int n = 0; n < 4; ++n)
            #pragma unroll
            for (int p = 0; p < 4; ++p) pm = fmaxf(pm, u_[n][p]);
        pm = fmaxf(pm, __shfl_xor(pm, 8, 64));
        pm = fmaxf(pm, __shfl_xor(pm, 16, 64));
        pm = fmaxf(pm, __shfl_xor(pm, 32, 64));
        if (lane < 8) redM[wv][lane] = pm;
        __syncthreads();   // bar 1

        // ---- umax fold (all lanes) ----
        float um = redM[0][j8];
        #pragma unroll
        for (int w = 1; w < NWAVE; ++w) um = fmaxf(um, redM[w][j8]);

        // ---- Phase B2: sums of a, eq, a*s, eq*s (JAX balanced-tie semantics) ----
        float pa = 0.f, pe = 0.f, pas = 0.f, pes = 0.f;
        #pragma unroll
        for (int n = 0; n < 4; ++n)
            #pragma unroll
            for (int p = 0; p < 4; ++p) {
                const float ss = sv_[n][p], u = u_[n][p];
                const float x = (u - um) + lm;
                const float a = (x > -lm) ? 1.0f : ((x == -lm) ? 0.5f : 0.0f);
                const float e = (u == um) ? 1.0f : 0.0f;
                pa += a; pe += e; pas += a * ss; pes += e * ss;
            }
        pa  += __shfl_xor(pa, 8, 64);  pa  += __shfl_xor(pa, 16, 64);  pa  += __shfl_xor(pa, 32, 64);
        pe  += __shfl_xor(pe, 8, 64);  pe  += __shfl_xor(pe, 16, 64);  pe  += __shfl_xor(pe, 32, 64);
        pas += __shfl_xor(pas, 8, 64); pas += __shfl_xor(pas, 16, 64); pas += __shfl_xor(pas, 32, 64);
        pes += __shfl_xor(pes, 8, 64); pes += __shfl_xor(pes, 16, 64); pes += __shfl_xor(pes, 32, 64);
        if (lane < 8) {
            f32x4 r4 = {pa, pe, pas, pes};
            *(f32x4*)&red2[wv][lane][0] = r4;
        }
        __syncthreads();   // bar 2

        // ---- sum fold (all lanes, b128 broadcast reads); c/lam update by wave 0 ----
        float sA = 0.f, sE = 0.f, sAS = 0.f, sES = 0.f;
        #pragma unroll
        for (int w = 0; w < NWAVE; ++w) {
            const f32x4 rr = *(const f32x4*)&red2[w][j8][0];
            sA += rr[0]; sE += rr[1]; sAS += rr[2]; sES += rr[3];
        }
        const float abar = sA * (1.0f / (float)NOBS);
        const float wA = (1.0f - abar) / sE;      // argmax weight / tie count
        const float gc = -2.0f * (sAS * (1.0f / (float)NOBS) + wA * sES);
        const float glam = (rho - 2.0f) + 2.0f * abar;
        if (wv == 0 && lane < 16) {               // consumed next iteration (after bar 5)
            cS[lane] = cS[lane] - lr * gc;
            lamS[lane] = fmaxf(lamS[lane] - lr * glam, 0.0f);
        }

        // ---- Phase B4: v = (a/n + eq*wA) * s -> bf16 hi/lo packed b64 into VT ----
        #pragma unroll
        for (int n = 0; n < 4; ++n) {
            u16x4 vh4, vl4;
            #pragma unroll
            for (int p = 0; p < 4; ++p) {
                const float ss = sv_[n][p], u = u_[n][p];
                const float x = (u - um) + lm;
                const float a = (x > -lm) ? 1.0f : ((x == -lm) ? 0.5f : 0.0f);
                const float e = (u == um) ? 1.0f : 0.0f;
                const float vv = (a * (1.0f / (float)NOBS) + e * wA) * ss;
                const unsigned short vhh = bf16_rne(vv);
                vh4[p] = vhh;
                vl4[p] = bf16_rne(vv - bf16_tof(vhh));
            }
            const int ii = ((wv << 3) + (hiHalf ? 4 : 0) + n) * 16 + (h << 2);
            *(u16x4*)&VT_hi[j8][ii] = vh4;
            *(u16x4*)&VT_lo[j8][ii] = vl4;
        }
        __syncthreads();   // bar 3

        // ---- Phase C: r = ep^T v via MFMA, 3-term 2-way split (R5-proven) ----
        {
            const int m = wv & 3;
            const int g = wv >> 2;
            f32x4 accC = {0.f, 0.f, 0.f, 0.f};
            #pragma unroll 4
            for (int qq = 0; qq < 16; ++qq) {
                const int q = g * 16 + qq;
                const int aoff = ((m * 64 + q) * 64 + lane) * 8;
                const short8 ah = *(const short8*)(epT_hi + aoff);
                const short8 al = *(const short8*)(epT_lo + aoff);
                const unsigned short* vh = (!hiHalf) ? &VT_hi[jb][(q << 5) + (h << 3)] : zb;
                const unsigned short* vl = (!hiHalf) ? &VT_lo[jb][(q << 5) + (h << 3)] : zb;
                const short8 bh = *(const short8*)vh;
                const short8 bl = *(const short8*)vl;
                accC = __builtin_amdgcn_mfma_f32_16x16x32_bf16(al, bh, accC, 0, 0, 0);
                accC = __builtin_amdgcn_mfma_f32_16x16x32_bf16(ah, bl, accC, 0, 0, 0);
                accC = __builtin_amdgcn_mfma_f32_16x16x32_bf16(ah, bh, accC, 0, 0, 0);
            }
            *(f32x4*)(&Rp2[g][m][lane][0]) = accC;
        }
        __syncthreads();   // bar 4

        // ---- Phase D: fold Rp2; update + simplex projection (wave j); z -> 3-way split ----
        if (wv < BS) {
            const int j = wv, k = lane;
            const int m = k >> 4, p = k & 3, ll = ((k >> 2) & 3) * 16 + j;
            const float r = Rp2[0][m][ll][p] + Rp2[1][m][ll][p]
                          + Rp2[2][m][ll][p] + Rp2[3][m][ll][p];
            const float gz = 2.0f * r - Yh[j][k];
            const float vz = Zs[j][k] - lr * gz;

            // bitonic sort (descending) across 64 lanes
            float sv2 = vz;
            #pragma unroll
            for (int sz = 2; sz <= 64; sz <<= 1) {
                #pragma unroll
                for (int st = sz >> 1; st > 0; st >>= 1) {
                    const float other = __shfl_xor(sv2, st, 64);
                    const bool desc = ((lane & sz) == 0);
                    const bool lower = ((lane & st) == 0);
                    const float mx = fmaxf(sv2, other), mn = fminf(sv2, other);
                    sv2 = (lower == desc) ? mx : mn;
                }
            }
            // inclusive scan -> cumsum - 1
            float css = sv2;
            #pragma unroll
            for (int off = 1; off < 64; off <<= 1) {
                const float nb = __shfl_up(css, off, 64);
                if (lane >= off) css += nb;
            }
            css -= 1.0f;
            const bool cond = (sv2 - css / (float)(lane + 1)) > 0.0f;
            const unsigned long long bal = __ballot(cond);
            const int idx = __popcll(bal) - 1;
            const float cssIdx = __shfl(css, idx, 64);
            const float theta = cssIdx / (float)(idx + 1);
            const float zk = fmaxf(vz - theta, 0.0f);
            Zs[j][k] = zk;
            const unsigned short zh_ = bf16_rne(zk);
            const float zr1 = zk - bf16_tof(zh_);
            const unsigned short zm_ = bf16_rne(zr1);
            const unsigned short zl_ = bf16_rne(zr1 - bf16_tof(zm_));
            Zb_hi[j][k] = zh_; Zb_hi[j + 8][k] = zh_;   // duplicate into cols 8..15
            Zb_md[j][k] = zm_; Zb_md[j + 8][k] = zm_;
            Zb_lo[j][k] = zl_; Zb_lo[j + 8][k] = zl_;
        }
        __syncthreads();   // bar 5
    }

    if (t < BS * NY) {
        const int j = t >> 6, k = t & 63;
        zout[(sc0 + j) * NY + k] = Zs[j][k];
    }
}

extern "C" void kernel_launch(void* const* d_in, const int* in_sizes, int n_in,
                              void* d_out, int out_size, void* d_ws, size_t ws_size,
                              hipStream_t stream) {
    const float* X   = (const float*)d_in[0];
    const float* Y   = (const float*)d_in[1];
    const float* rho = (const float*)d_in[2];
    const float* W   = (const float*)d_in[3];
    const float* b   = (const float*)d_in[4];

    float* out   = (float*)d_out;
    float* zout  = out;                 // Z_star: 2048*64
    float* yhat  = out + NOBS * NY;     // Y_hat:  2048*64

    // workspace: epT_hi | epT_lo | epA_hi | epA_md | epA_lo | epsum  (1.25 MB + 4 B)
    unsigned short* epT_hi = (unsigned short*)d_ws;              // 256 KB
    unsigned short* epT_lo = epT_hi + NY * NOBS;                 // 256 KB
    unsigned short* epA_hi = epT_lo + NY * NOBS;                 // 256 KB
    unsigned short* epA_md = epA_hi + NY * NOBS;                 // 256 KB
    unsigned short* epA_lo = epA_md + NY * NOBS;                 // 256 KB
    float* epsum = (float*)(epA_lo + NY * NOBS);                 // 1 f32

    hipMemsetAsync(epsum, 0, sizeof(float), stream);
    prep_kernel<<<NOBS / 4, 256, 0, stream>>>(X, Y, W, b, yhat, epsum,
                                              epT_hi, epT_lo, epA_hi, epA_md, epA_lo);
    solve_kernel<<<NOBS / BS, NT, 0, stream>>>(yhat, epsum, rho,
                                               epT_hi, epT_lo, epA_hi, epA_md, epA_lo, zout);
}

// Round 8
// 3267.210 us; speedup vs baseline: 1.0056x; 1.0056x over previous
//
#include <hip/hip_runtime.h>

#define NOBS 2048
#define NX   128
#define NY   64
#define BS   8            // scenarios per solver block (256 blocks, 1/CU, all resident)
#define NT   1024         // 16 waves
#define NWAVE (NT / 64)
#define NITER 64

typedef short short8 __attribute__((ext_vector_type(8)));   // 8 bf16 (4 VGPRs)
typedef float f32x4 __attribute__((ext_vector_type(4)));    // MFMA accumulator
typedef unsigned short u16x4 __attribute__((ext_vector_type(4)));

// ---- bf16 split helpers (RNE) ----
__device__ __forceinline__ unsigned short bf16_rne(float x) {
    unsigned u = __float_as_uint(x);
    return (unsigned short)((u + 0x7FFFu + ((u >> 16) & 1u)) >> 16);
}
__device__ __forceinline__ float bf16_tof(unsigned short h) {
    return __uint_as_float(((unsigned)h) << 16);
}

// ---- DPP wave reduction (prep only) ----
template <int CTRL>
__device__ __forceinline__ float dpp_f(float x) {
    return __int_as_float(__builtin_amdgcn_update_dpp(
        0, __float_as_int(x), CTRL, 0xf, 0xf, true));
}
__device__ __forceinline__ float wave_sum64(float v) {
    v += dpp_f<0x111>(v);
    v += dpp_f<0x112>(v);
    v += dpp_f<0x114>(v);
    v += dpp_f<0x118>(v);
    v += dpp_f<0x142>(v);
    v += dpp_f<0x143>(v);   // lane 63 = total
    return v;
}

// ---- Kernel 1: Y_hat = X@W^T + b ; epsum ; ep bf16 3-way split (two layouts) ----
// e = hi + md + lo + r, |r| <~ 2^-24 |e|.  epT uses (hi, md) [2-way], epA uses all 3.
__global__ __launch_bounds__(256) void prep_kernel(
    const float* __restrict__ X, const float* __restrict__ Y,
    const float* __restrict__ W, const float* __restrict__ b,
    float* __restrict__ yhat_out, float* __restrict__ epsum,
    unsigned short* __restrict__ epT_hi, unsigned short* __restrict__ epT_lo,
    unsigned short* __restrict__ epA_hi, unsigned short* __restrict__ epA_md,
    unsigned short* __restrict__ epA_lo)
{
    __shared__ float Xs[4][NX];
    const int t = threadIdx.x;
    const int row0 = blockIdx.x * 4;
    for (int f = t; f < 4 * NX; f += 256)
        Xs[f >> 7][f & 127] = X[(row0 + (f >> 7)) * NX + (f & 127)];
    __syncthreads();

    const int k = t & 63;
    const int r = t >> 6;
    const float4* W4 = reinterpret_cast<const float4*>(W + k * NX);
    const float4* X4 = reinterpret_cast<const float4*>(&Xs[r][0]);
    float acc = 0.f;
    #pragma unroll
    for (int x = 0; x < NX / 4; ++x) {
        float4 wv = W4[x];
        float4 xv = X4[x];
        acc += wv.x * xv.x + wv.y * xv.y + wv.z * xv.z + wv.w * xv.w;
    }
    const float yh = acc + b[k];
    const int i = row0 + r;
    yhat_out[i * NY + k] = yh;
    const float e = Y[i * NY + k] - yh;

    const unsigned short hi = bf16_rne(e);
    const float r1 = e - bf16_tof(hi);
    const unsigned short md = bf16_rne(r1);
    const unsigned short lo = bf16_rne(r1 - bf16_tof(md));
    // Phase C A-frag (rows = k, K = i):  A[row=lane&15][kk=8*(lane>>4)+d]
    {
        const int m  = k >> 4;
        const int q  = i >> 5;
        const int lc = (k & 15) + 16 * ((i >> 3) & 3);
        const int d  = i & 7;
        const int idx = ((m * 64 + q) * 64 + lc) * 8 + d;
        epT_hi[idx] = hi;
        epT_lo[idx] = md;
    }
    // Phase A A-frag (rows = i, K = k)
    {
        const int m  = i >> 4;
        const int q  = k >> 5;
        const int lc = (i & 15) + 16 * ((k >> 3) & 3);
        const int d  = k & 7;
        const int idx = ((m * 2 + q) * 64 + lc) * 8 + d;
        epA_hi[idx] = hi;
        epA_md[idx] = md;
        epA_lo[idx] = lo;
    }

    float se = wave_sum64(e);
    if ((t & 63) == 63) atomicAdd(epsum, se);
}

// ---- Kernel 2: batched projected-subgradient DRO solve ----
// Phase A on MFMA, 3-way split, TWO PASSES of 4 m-tiles (acc[4]) to stay
// under the 128-VGPR cap (R7 spilled: 7.1 GB scratch FETCH). Phase C 2-way
// split (R5-proven). u recomputed from s (no u_ array). 5 barriers/iter.
__global__ __launch_bounds__(NT, 4) void solve_kernel(
    const float* __restrict__ yhat, const float* __restrict__ epsum,
    const float* __restrict__ rho_p,
    const unsigned short* __restrict__ epT_hi, const unsigned short* __restrict__ epT_lo,
    const unsigned short* __restrict__ epA_hi, const unsigned short* __restrict__ epA_md,
    const unsigned short* __restrict__ epA_lo,
    float* __restrict__ zout)
{
    __shared__ float Zs[BS][NY];                 // 2 KB
    __shared__ float Yh[BS][NY];                 // 2 KB
    __shared__ unsigned short VT_hi[BS][2056];   // 32.1 KB
    __shared__ unsigned short VT_lo[BS][2056];   // 32.1 KB
    __shared__ __align__(16) unsigned short Zb_hi[16][72];  // 2.25 KB (cols 8..15 dup)
    __shared__ __align__(16) unsigned short Zb_md[16][72];  // 2.25 KB
    __shared__ __align__(16) unsigned short Zb_lo[16][72];  // 2.25 KB
    __shared__ float Rp2[4][4][64][4];           // 16 KB  [g][m][lane][reg]
    __shared__ float redM[NWAVE][BS];            // per-wave umax partials
    __shared__ float red2[NWAVE][BS][4];         // per-wave {pa,pe,pas,pes}
    __shared__ float cS[16], lamS[16];           // cols 8..15 dup
    __shared__ __align__(16) unsigned short zb[8];

    const int t = threadIdx.x;
    const int lane = t & 63;
    const int wv = t >> 6;
    const int jb = lane & 15;      // MFMA column
    const int h  = lane >> 4;      // frag k-chunk / row-group
    const int j8 = jb & 7;         // actual scenario
    const bool hiHalf = (jb >= 8);
    const int sc0 = blockIdx.x * BS;
    const float rho = rho_p[0];

    if (t < BS * NY) {
        const int j = t >> 6, k = t & 63;
        Yh[j][k] = yhat[(sc0 + j) * NY + k];
        Zs[j][k] = 1.0f / 64.0f;
    }
    {   // z0 = 1/64 exact in bf16 (power of two) -> md = lo = 0
        const int j = t >> 6, k = t & 63;
        Zb_hi[j][k] = bf16_rne(1.0f / 64.0f);
        Zb_md[j][k] = 0;
        Zb_lo[j][k] = 0;
    }
    if (t < 16) {
        cS[t] = epsum[0] * (1.0f / 131072.0f);  // mean(ep) == mean(ep @ z0)
        lamS[t] = 1.0f;
    }
    if (t < 8) zb[t] = 0;
    __syncthreads();

    for (int it = 0; it < NITER; ++it) {
        const float lr = 0.05f / sqrtf((float)it + 1.0f);

        const float cR = cS[jb];
        const float lm = lamS[jb];

        // ---- Phase A: S = ep.z - c via MFMA, 6-term 3-way split, two passes ----
        // pass 0: m-tiles 0..3 (lo-half lanes extract); pass 1: tiles 4..7 (hi-half).
        float sv_[4][4];
        #pragma unroll
        for (int pass = 0; pass < 2; ++pass) {
            f32x4 acc[4];
            #pragma unroll
            for (int n = 0; n < 4; ++n) acc[n] = (f32x4){0.f, 0.f, 0.f, 0.f};
            #pragma unroll
            for (int q = 0; q < 2; ++q) {
                const short8 zh = *(const short8*)&Zb_hi[jb][(q << 5) + (h << 3)];
                const short8 zm = *(const short8*)&Zb_md[jb][(q << 5) + (h << 3)];
                const short8 zl = *(const short8*)&Zb_lo[jb][(q << 5) + (h << 3)];
                #pragma unroll
                for (int n = 0; n < 4; ++n) {
                    const int mi = pass * 4 + n;
                    const int aoff = ((((wv << 3) + mi) * 2 + q) * 64 + lane) * 8;
                    const short8 ah = *(const short8*)(epA_hi + aoff);
                    const short8 am = *(const short8*)(epA_md + aoff);
                    const short8 al = *(const short8*)(epA_lo + aoff);
                    acc[n] = __builtin_amdgcn_mfma_f32_16x16x32_bf16(al, zh, acc[n], 0, 0, 0); // lH
                    acc[n] = __builtin_amdgcn_mfma_f32_16x16x32_bf16(ah, zl, acc[n], 0, 0, 0); // hL
                    acc[n] = __builtin_amdgcn_mfma_f32_16x16x32_bf16(am, zm, acc[n], 0, 0, 0); // mM
                    acc[n] = __builtin_amdgcn_mfma_f32_16x16x32_bf16(am, zh, acc[n], 0, 0, 0); // mH
                    acc[n] = __builtin_amdgcn_mfma_f32_16x16x32_bf16(ah, zm, acc[n], 0, 0, 0); // hM
                    acc[n] = __builtin_amdgcn_mfma_f32_16x16x32_bf16(ah, zh, acc[n], 0, 0, 0); // hH
                }
            }
            const bool take = (hiHalf == (pass == 1));
            #pragma unroll
            for (int n = 0; n < 4; ++n)
                #pragma unroll
                for (int p = 0; p < 4; ++p)
                    if (take) sv_[n][p] = acc[n][p] - cR;  // s for i = 16*(8wv+4*pass+n)+4h+p
            __builtin_amdgcn_sched_barrier(0);   // keep passes separate (cap acc liveness)
        }

        // ---- Phase B1: per-wave umax (in-lane 16 -> xor 8/16/32); u = s*s recomputed ----
        float pm = sv_[0][0] * sv_[0][0];
        #pragma unroll
        for (int n = 0; n < 4; ++n)
            #pragma unroll
            for (int p = 0; p < 4; ++p) pm = fmaxf(pm, sv_[n][p] * sv_[n][p]);
        pm = fmaxf(pm, __shfl_xor(pm, 8, 64));
        pm = fmaxf(pm, __shfl_xor(pm, 16, 64));
        pm = fmaxf(pm, __shfl_xor(pm, 32, 64));
        if (lane < 8) redM[wv][lane] = pm;
        __syncthreads();   // bar 1

        // ---- umax fold (all lanes) ----
        float um = redM[0][j8];
        #pragma unroll
        for (int w = 1; w < NWAVE; ++w) um = fmaxf(um, redM[w][j8]);

        // ---- Phase B2: sums of a, eq, a*s, eq*s (JAX balanced-tie semantics) ----
        float pa = 0.f, pe = 0.f, pas = 0.f, pes = 0.f;
        #pragma unroll
        for (int n = 0; n < 4; ++n)
            #pragma unroll
            for (int p = 0; p < 4; ++p) {
                const float ss = sv_[n][p], u = ss * ss;
                const float x = (u - um) + lm;
                const float a = (x > -lm) ? 1.0f : ((x == -lm) ? 0.5f : 0.0f);
                const float e = (u == um) ? 1.0f : 0.0f;
                pa += a; pe += e; pas += a * ss; pes += e * ss;
            }
        pa  += __shfl_xor(pa, 8, 64);  pa  += __shfl_xor(pa, 16, 64);  pa  += __shfl_xor(pa, 32, 64);
        pe  += __shfl_xor(pe, 8, 64);  pe  += __shfl_xor(pe, 16, 64);  pe  += __shfl_xor(pe, 32, 64);
        pas += __shfl_xor(pas, 8, 64); pas += __shfl_xor(pas, 16, 64); pas += __shfl_xor(pas, 32, 64);
        pes += __shfl_xor(pes, 8, 64); pes += __shfl_xor(pes, 16, 64); pes += __shfl_xor(pes, 32, 64);
        if (lane < 8) {
            f32x4 r4 = {pa, pe, pas, pes};
            *(f32x4*)&red2[wv][lane][0] = r4;
        }
        __syncthreads();   // bar 2

        // ---- sum fold (all lanes, b128 broadcast reads); c/lam update by wave 0 ----
        float sA = 0.f, sE = 0.f, sAS = 0.f, sES = 0.f;
        #pragma unroll
        for (int w = 0; w < NWAVE; ++w) {
            const f32x4 rr = *(const f32x4*)&red2[w][j8][0];
            sA += rr[0]; sE += rr[1]; sAS += rr[2]; sES += rr[3];
        }
        const float abar = sA * (1.0f / (float)NOBS);
        const float wA = (1.0f - abar) / sE;      // argmax weight / tie count
        const float gc = -2.0f * (sAS * (1.0f / (float)NOBS) + wA * sES);
        const float glam = (rho - 2.0f) + 2.0f * abar;
        if (wv == 0 && lane < 16) {               // consumed next iteration (after bar 5)
            cS[lane] = cS[lane] - lr * gc;
            lamS[lane] = fmaxf(lamS[lane] - lr * glam, 0.0f);
        }

        // ---- Phase B4: v = (a/n + eq*wA) * s -> bf16 hi/lo packed b64 into VT ----
        #pragma unroll
        for (int n = 0; n < 4; ++n) {
            u16x4 vh4, vl4;
            #pragma unroll
            for (int p = 0; p < 4; ++p) {
                const float ss = sv_[n][p], u = ss * ss;
                const float x = (u - um) + lm;
                const float a = (x > -lm) ? 1.0f : ((x == -lm) ? 0.5f : 0.0f);
                const float e = (u == um) ? 1.0f : 0.0f;
                const float vv = (a * (1.0f / (float)NOBS) + e * wA) * ss;
                const unsigned short vhh = bf16_rne(vv);
                vh4[p] = vhh;
                vl4[p] = bf16_rne(vv - bf16_tof(vhh));
            }
            const int ii = ((wv << 3) + (hiHalf ? 4 : 0) + n) * 16 + (h << 2);
            *(u16x4*)&VT_hi[j8][ii] = vh4;
            *(u16x4*)&VT_lo[j8][ii] = vl4;
        }
        __syncthreads();   // bar 3

        // ---- Phase C: r = ep^T v via MFMA, 3-term 2-way split (R5-proven) ----
        {
            const int m = wv & 3;
            const int g = wv >> 2;
            f32x4 accC = {0.f, 0.f, 0.f, 0.f};
            #pragma unroll 4
            for (int qq = 0; qq < 16; ++qq) {
                const int q = g * 16 + qq;
                const int aoff = ((m * 64 + q) * 64 + lane) * 8;
                const short8 ah = *(const short8*)(epT_hi + aoff);
                const short8 al = *(const short8*)(epT_lo + aoff);
                const unsigned short* vh = (!hiHalf) ? &VT_hi[jb][(q << 5) + (h << 3)] : zb;
                const unsigned short* vl = (!hiHalf) ? &VT_lo[jb][(q << 5) + (h << 3)] : zb;
                const short8 bh = *(const short8*)vh;
                const short8 bl = *(const short8*)vl;
                accC = __builtin_amdgcn_mfma_f32_16x16x32_bf16(al, bh, accC, 0, 0, 0);
                accC = __builtin_amdgcn_mfma_f32_16x16x32_bf16(ah, bl, accC, 0, 0, 0);
                accC = __builtin_amdgcn_mfma_f32_16x16x32_bf16(ah, bh, accC, 0, 0, 0);
            }
            *(f32x4*)(&Rp2[g][m][lane][0]) = accC;
        }
        __syncthreads();   // bar 4

        // ---- Phase D: fold Rp2; update + simplex projection (wave j); z -> 3-way split ----
        if (wv < BS) {
            const int j = wv, k = lane;
            const int m = k >> 4, p = k & 3, ll = ((k >> 2) & 3) * 16 + j;
            const float r = Rp2[0][m][ll][p] + Rp2[1][m][ll][p]
                          + Rp2[2][m][ll][p] + Rp2[3][m][ll][p];
            const float gz = 2.0f * r - Yh[j][k];
            const float vz = Zs[j][k] - lr * gz;

            // bitonic sort (descending) across 64 lanes
            float sv2 = vz;
            #pragma unroll
            for (int sz = 2; sz <= 64; sz <<= 1) {
                #pragma unroll
                for (int st = sz >> 1; st > 0; st >>= 1) {
                    const float other = __shfl_xor(sv2, st, 64);
                    const bool desc = ((lane & sz) == 0);
                    const bool lower = ((lane & st) == 0);
                    const float mx = fmaxf(sv2, other), mn = fminf(sv2, other);
                    sv2 = (lower == desc) ? mx : mn;
                }
            }
            // inclusive scan -> cumsum - 1
            float css = sv2;
            #pragma unroll
            for (int off = 1; off < 64; off <<= 1) {
                const float nb = __shfl_up(css, off, 64);
                if (lane >= off) css += nb;
            }
            css -= 1.0f;
            const bool cond = (sv2 - css / (float)(lane + 1)) > 0.0f;
            const unsigned long long bal = __ballot(cond);
            const int idx = __popcll(bal) - 1;
            const float cssIdx = __shfl(css, idx, 64);
            const float theta = cssIdx / (float)(idx + 1);
            const float zk = fmaxf(vz - theta, 0.0f);
            Zs[j][k] = zk;
            const unsigned short zh_ = bf16_rne(zk);
            const float zr1 = zk - bf16_tof(zh_);
            const unsigned short zm_ = bf16_rne(zr1);
            const unsigned short zl_ = bf16_rne(zr1 - bf16_tof(zm_));
            Zb_hi[j][k] = zh_; Zb_hi[j + 8][k] = zh_;   // duplicate into cols 8..15
            Zb_md[j][k] = zm_; Zb_md[j + 8][k] = zm_;
            Zb_lo[j][k] = zl_; Zb_lo[j + 8][k] = zl_;
        }
        __syncthreads();   // bar 5
    }

    if (t < BS * NY) {
        const int j = t >> 6, k = t & 63;
        zout[(sc0 + j) * NY + k] = Zs[j][k];
    }
}

extern "C" void kernel_launch(void* const* d_in, const int* in_sizes, int n_in,
                              void* d_out, int out_size, void* d_ws, size_t ws_size,
                              hipStream_t stream) {
    const float* X   = (const float*)d_in[0];
    const float* Y   = (const float*)d_in[1];
    const float* rho = (const float*)d_in[2];
    const float* W   = (const float*)d_in[3];
    const float* b   = (const float*)d_in[4];

    float* out   = (float*)d_out;
    float* zout  = out;                 // Z_star: 2048*64
    float* yhat  = out + NOBS * NY;     // Y_hat:  2048*64

    // workspace: epT_hi | epT_lo | epA_hi | epA_md | epA_lo | epsum  (1.25 MB + 4 B)
    unsigned short* epT_hi = (unsigned short*)d_ws;              // 256 KB
    unsigned short* epT_lo = epT_hi + NY * NOBS;                 // 256 KB
    unsigned short* epA_hi = epT_lo + NY * NOBS;                 // 256 KB
    unsigned short* epA_md = epA_hi + NY * NOBS;                 // 256 KB
    unsigned short* epA_lo = epA_md + NY * NOBS;                 // 256 KB
    float* epsum = (float*)(epA_lo + NY * NOBS);                 // 1 f32

    hipMemsetAsync(epsum, 0, sizeof(float), stream);
    prep_kernel<<<NOBS / 4, 256, 0, stream>>>(X, Y, W, b, yhat, epsum,
                                              epT_hi, epT_lo, epA_hi, epA_md, epA_lo);
    solve_kernel<<<NOBS / BS, NT, 0, stream>>>(yhat, epsum, rho,
                                               epT_hi, epT_lo, epA_hi, epA_md, epA_lo, zout);
}

// Round 9
// 3253.079 us; speedup vs baseline: 1.0100x; 1.0043x over previous
//
#include <hip/hip_runtime.h>

#define NOBS 2048
#define NX   128
#define NY   64
#define BS   8            // scenarios per solver block (256 blocks, 1/CU, all resident)
#define NT   1024         // 16 waves
#define NWAVE (NT / 64)
#define NITER 64

typedef short short8 __attribute__((ext_vector_type(8)));   // 8 bf16 (4 VGPRs)
typedef float f32x4 __attribute__((ext_vector_type(4)));    // MFMA accumulator
typedef unsigned short u16x4 __attribute__((ext_vector_type(4)));

// ---- bf16 split helpers (RNE) ----
__device__ __forceinline__ unsigned short bf16_rne(float x) {
    unsigned u = __float_as_uint(x);
    return (unsigned short)((u + 0x7FFFu + ((u >> 16) & 1u)) >> 16);
}
__device__ __forceinline__ float bf16_tof(unsigned short h) {
    return __uint_as_float(((unsigned)h) << 16);
}

// ---- DPP wave reduction (prep only) ----
template <int CTRL>
__device__ __forceinline__ float dpp_f(float x) {
    return __int_as_float(__builtin_amdgcn_update_dpp(
        0, __float_as_int(x), CTRL, 0xf, 0xf, true));
}
__device__ __forceinline__ float wave_sum64(float v) {
    v += dpp_f<0x111>(v);
    v += dpp_f<0x112>(v);
    v += dpp_f<0x114>(v);
    v += dpp_f<0x118>(v);
    v += dpp_f<0x142>(v);
    v += dpp_f<0x143>(v);   // lane 63 = total
    return v;
}

// ---- Kernel 1: Y_hat = X@W^T + b ; epsum ; ep bf16 3-way split (two layouts) ----
// e = hi + md + lo + r, |r| <~ 2^-24 |e|.  epT uses (hi, md) [2-way], epA uses all 3.
__global__ __launch_bounds__(256) void prep_kernel(
    const float* __restrict__ X, const float* __restrict__ Y,
    const float* __restrict__ W, const float* __restrict__ b,
    float* __restrict__ yhat_out, float* __restrict__ epsum,
    unsigned short* __restrict__ epT_hi, unsigned short* __restrict__ epT_lo,
    unsigned short* __restrict__ epA_hi, unsigned short* __restrict__ epA_md,
    unsigned short* __restrict__ epA_lo)
{
    __shared__ float Xs[4][NX];
    const int t = threadIdx.x;
    const int row0 = blockIdx.x * 4;
    for (int f = t; f < 4 * NX; f += 256)
        Xs[f >> 7][f & 127] = X[(row0 + (f >> 7)) * NX + (f & 127)];
    __syncthreads();

    const int k = t & 63;
    const int r = t >> 6;
    const float4* W4 = reinterpret_cast<const float4*>(W + k * NX);
    const float4* X4 = reinterpret_cast<const float4*>(&Xs[r][0]);
    float acc = 0.f;
    #pragma unroll
    for (int x = 0; x < NX / 4; ++x) {
        float4 wv = W4[x];
        float4 xv = X4[x];
        acc += wv.x * xv.x + wv.y * xv.y + wv.z * xv.z + wv.w * xv.w;
    }
    const float yh = acc + b[k];
    const int i = row0 + r;
    yhat_out[i * NY + k] = yh;
    const float e = Y[i * NY + k] - yh;

    const unsigned short hi = bf16_rne(e);
    const float r1 = e - bf16_tof(hi);
    const unsigned short md = bf16_rne(r1);
    const unsigned short lo = bf16_rne(r1 - bf16_tof(md));
    // Phase C A-frag (rows = k, K = i):  A[row=lane&15][kk=8*(lane>>4)+d]
    {
        const int m  = k >> 4;
        const int q  = i >> 5;
        const int lc = (k & 15) + 16 * ((i >> 3) & 3);
        const int d  = i & 7;
        const int idx = ((m * 64 + q) * 64 + lc) * 8 + d;
        epT_hi[idx] = hi;
        epT_lo[idx] = md;
    }
    // Phase A A-frag (rows = i, K = k)
    {
        const int m  = i >> 4;
        const int q  = k >> 5;
        const int lc = (i & 15) + 16 * ((k >> 3) & 3);
        const int d  = k & 7;
        const int idx = ((m * 2 + q) * 64 + lc) * 8 + d;
        epA_hi[idx] = hi;
        epA_md[idx] = md;
        epA_lo[idx] = lo;
    }

    float se = wave_sum64(e);
    if ((t & 63) == 63) atomicAdd(epsum, se);
}

// ---- Kernel 2: batched projected-subgradient DRO solve ----
// Phase A on MFMA (3-way split, 6 terms, two passes of 4 m-tiles); Phase C on
// MFMA (2-way split, 3 terms). 5 barriers/iter.
// launch_bounds min-waves arg = 2: empirically this compiler caps VGPR at
// 256/arg (R1: arg8->32, R0..R8: arg4->64 -> spill); arg2 -> 128 cap, and the
// 1024-thread block independently needs <=128, so occupancy is unchanged
// (LDS 96 KB already limits to 1 block/CU).
__global__ __launch_bounds__(NT, 2) void solve_kernel(
    const float* __restrict__ yhat, const float* __restrict__ epsum,
    const float* __restrict__ rho_p,
    const unsigned short* __restrict__ epT_hi, const unsigned short* __restrict__ epT_lo,
    const unsigned short* __restrict__ epA_hi, const unsigned short* __restrict__ epA_md,
    const unsigned short* __restrict__ epA_lo,
    float* __restrict__ zout)
{
    __shared__ float Zs[BS][NY];                 // 2 KB
    __shared__ float Yh[BS][NY];                 // 2 KB
    __shared__ unsigned short VT_hi[BS][2056];   // 32.1 KB
    __shared__ unsigned short VT_lo[BS][2056];   // 32.1 KB
    __shared__ __align__(16) unsigned short Zb_hi[16][72];  // 2.25 KB (cols 8..15 dup)
    __shared__ __align__(16) unsigned short Zb_md[16][72];  // 2.25 KB
    __shared__ __align__(16) unsigned short Zb_lo[16][72];  // 2.25 KB
    __shared__ float Rp2[4][4][64][4];           // 16 KB  [g][m][lane][reg]
    __shared__ float redM[NWAVE][BS];            // per-wave umax partials
    __shared__ float red2[NWAVE][BS][4];         // per-wave {pa,pe,pas,pes}
    __shared__ float cS[16], lamS[16];           // cols 8..15 dup
    __shared__ __align__(16) unsigned short zb[8];

    const int t = threadIdx.x;
    const int lane = t & 63;
    const int wv = t >> 6;
    const int jb = lane & 15;      // MFMA column
    const int h  = lane >> 4;      // frag k-chunk / row-group
    const int j8 = jb & 7;         // actual scenario
    const bool hiHalf = (jb >= 8);
    const int sc0 = blockIdx.x * BS;
    const float rho = rho_p[0];

    if (t < BS * NY) {
        const int j = t >> 6, k = t & 63;
        Yh[j][k] = yhat[(sc0 + j) * NY + k];
        Zs[j][k] = 1.0f / 64.0f;
    }
    {   // z0 = 1/64 exact in bf16 (power of two) -> md = lo = 0
        const int j = t >> 6, k = t & 63;
        Zb_hi[j][k] = bf16_rne(1.0f / 64.0f);
        Zb_md[j][k] = 0;
        Zb_lo[j][k] = 0;
    }
    if (t < 16) {
        cS[t] = epsum[0] * (1.0f / 131072.0f);  // mean(ep) == mean(ep @ z0)
        lamS[t] = 1.0f;
    }
    if (t < 8) zb[t] = 0;
    __syncthreads();

    for (int it = 0; it < NITER; ++it) {
        const float lr = 0.05f / sqrtf((float)it + 1.0f);

        const float cR = cS[jb];
        const float lm = lamS[jb];

        // ---- Phase A: S = ep.z - c via MFMA, 6-term 3-way split, two passes ----
        // pass 0: m-tiles 0..3 (lo-half lanes extract); pass 1: tiles 4..7 (hi-half).
        float sv_[4][4];
        #pragma unroll
        for (int pass = 0; pass < 2; ++pass) {
            f32x4 acc[4];
            #pragma unroll
            for (int n = 0; n < 4; ++n) acc[n] = (f32x4){0.f, 0.f, 0.f, 0.f};
            #pragma unroll
            for (int q = 0; q < 2; ++q) {
                const short8 zh = *(const short8*)&Zb_hi[jb][(q << 5) + (h << 3)];
                const short8 zm = *(const short8*)&Zb_md[jb][(q << 5) + (h << 3)];
                const short8 zl = *(const short8*)&Zb_lo[jb][(q << 5) + (h << 3)];
                #pragma unroll
                for (int n = 0; n < 4; ++n) {
                    const int mi = pass * 4 + n;
                    const int aoff = ((((wv << 3) + mi) * 2 + q) * 64 + lane) * 8;
                    const short8 ah = *(const short8*)(epA_hi + aoff);
                    const short8 am = *(const short8*)(epA_md + aoff);
                    const short8 al = *(const short8*)(epA_lo + aoff);
                    acc[n] = __builtin_amdgcn_mfma_f32_16x16x32_bf16(al, zh, acc[n], 0, 0, 0); // lH
                    acc[n] = __builtin_amdgcn_mfma_f32_16x16x32_bf16(ah, zl, acc[n], 0, 0, 0); // hL
                    acc[n] = __builtin_amdgcn_mfma_f32_16x16x32_bf16(am, zm, acc[n], 0, 0, 0); // mM
                    acc[n] = __builtin_amdgcn_mfma_f32_16x16x32_bf16(am, zh, acc[n], 0, 0, 0); // mH
                    acc[n] = __builtin_amdgcn_mfma_f32_16x16x32_bf16(ah, zm, acc[n], 0, 0, 0); // hM
                    acc[n] = __builtin_amdgcn_mfma_f32_16x16x32_bf16(ah, zh, acc[n], 0, 0, 0); // hH
                }
            }
            const bool take = (hiHalf == (pass == 1));
            #pragma unroll
            for (int n = 0; n < 4; ++n)
                #pragma unroll
                for (int p = 0; p < 4; ++p)
                    if (take) sv_[n][p] = acc[n][p] - cR;  // s for i = 16*(8wv+4*pass+n)+4h+p
            __builtin_amdgcn_sched_barrier(0);   // keep passes separate (cap acc liveness)
        }

        // ---- Phase B1: per-wave umax (in-lane 16 -> xor 8/16/32); u = s*s recomputed ----
        float pm = sv_[0][0] * sv_[0][0];
        #pragma unroll
        for (int n = 0; n < 4; ++n)
            #pragma unroll
            for (int p = 0; p < 4; ++p) pm = fmaxf(pm, sv_[n][p] * sv_[n][p]);
        pm = fmaxf(pm, __shfl_xor(pm, 8, 64));
        pm = fmaxf(pm, __shfl_xor(pm, 16, 64));
        pm = fmaxf(pm, __shfl_xor(pm, 32, 64));
        if (lane < 8) redM[wv][lane] = pm;
        __syncthreads();   // bar 1

        // ---- umax fold (all lanes) ----
        float um = redM[0][j8];
        #pragma unroll
        for (int w = 1; w < NWAVE; ++w) um = fmaxf(um, redM[w][j8]);

        // ---- Phase B2: sums of a, eq, a*s, eq*s (JAX balanced-tie semantics) ----
        float pa = 0.f, pe = 0.f, pas = 0.f, pes = 0.f;
        #pragma unroll
        for (int n = 0; n < 4; ++n)
            #pragma unroll
            for (int p = 0; p < 4; ++p) {
                const float ss = sv_[n][p], u = ss * ss;
                const float x = (u - um) + lm;
                const float a = (x > -lm) ? 1.0f : ((x == -lm) ? 0.5f : 0.0f);
                const float e = (u == um) ? 1.0f : 0.0f;
                pa += a; pe += e; pas += a * ss; pes += e * ss;
            }
        pa  += __shfl_xor(pa, 8, 64);  pa  += __shfl_xor(pa, 16, 64);  pa  += __shfl_xor(pa, 32, 64);
        pe  += __shfl_xor(pe, 8, 64);  pe  += __shfl_xor(pe, 16, 64);  pe  += __shfl_xor(pe, 32, 64);
        pas += __shfl_xor(pas, 8, 64); pas += __shfl_xor(pas, 16, 64); pas += __shfl_xor(pas, 32, 64);
        pes += __shfl_xor(pes, 8, 64); pes += __shfl_xor(pes, 16, 64); pes += __shfl_xor(pes, 32, 64);
        if (lane < 8) {
            f32x4 r4 = {pa, pe, pas, pes};
            *(f32x4*)&red2[wv][lane][0] = r4;
        }
        __syncthreads();   // bar 2

        // ---- sum fold (all lanes, b128 broadcast reads); c/lam update by wave 0 ----
        float sA = 0.f, sE = 0.f, sAS = 0.f, sES = 0.f;
        #pragma unroll
        for (int w = 0; w < NWAVE; ++w) {
            const f32x4 rr = *(const f32x4*)&red2[w][j8][0];
            sA += rr[0]; sE += rr[1]; sAS += rr[2]; sES += rr[3];
        }
        const float abar = sA * (1.0f / (float)NOBS);
        const float wA = (1.0f - abar) / sE;      // argmax weight / tie count
        const float gc = -2.0f * (sAS * (1.0f / (float)NOBS) + wA * sES);
        const float glam = (rho - 2.0f) + 2.0f * abar;
        if (wv == 0 && lane < 16) {               // consumed next iteration (after bar 5)
            cS[lane] = cS[lane] - lr * gc;
            lamS[lane] = fmaxf(lamS[lane] - lr * glam, 0.0f);
        }

        // ---- Phase B4: v = (a/n + eq*wA) * s -> bf16 hi/lo packed b64 into VT ----
        #pragma unroll
        for (int n = 0; n < 4; ++n) {
            u16x4 vh4, vl4;
            #pragma unroll
            for (int p = 0; p < 4; ++p) {
                const float ss = sv_[n][p], u = ss * ss;
                const float x = (u - um) + lm;
                const float a = (x > -lm) ? 1.0f : ((x == -lm) ? 0.5f : 0.0f);
                const float e = (u == um) ? 1.0f : 0.0f;
                const float vv = (a * (1.0f / (float)NOBS) + e * wA) * ss;
                const unsigned short vhh = bf16_rne(vv);
                vh4[p] = vhh;
                vl4[p] = bf16_rne(vv - bf16_tof(vhh));
            }
            const int ii = ((wv << 3) + (hiHalf ? 4 : 0) + n) * 16 + (h << 2);
            *(u16x4*)&VT_hi[j8][ii] = vh4;
            *(u16x4*)&VT_lo[j8][ii] = vl4;
        }
        __syncthreads();   // bar 3

        // ---- Phase C: r = ep^T v via MFMA, 3-term 2-way split (R5-proven) ----
        {
            const int m = wv & 3;
            const int g = wv >> 2;
            f32x4 accC = {0.f, 0.f, 0.f, 0.f};
            #pragma unroll 4
            for (int qq = 0; qq < 16; ++qq) {
                const int q = g * 16 + qq;
                const int aoff = ((m * 64 + q) * 64 + lane) * 8;
                const short8 ah = *(const short8*)(epT_hi + aoff);
                const short8 al = *(const short8*)(epT_lo + aoff);
                const unsigned short* vh = (!hiHalf) ? &VT_hi[jb][(q << 5) + (h << 3)] : zb;
                const unsigned short* vl = (!hiHalf) ? &VT_lo[jb][(q << 5) + (h << 3)] : zb;
                const short8 bh = *(const short8*)vh;
                const short8 bl = *(const short8*)vl;
                accC = __builtin_amdgcn_mfma_f32_16x16x32_bf16(al, bh, accC, 0, 0, 0);
                accC = __builtin_amdgcn_mfma_f32_16x16x32_bf16(ah, bl, accC, 0, 0, 0);
                accC = __builtin_amdgcn_mfma_f32_16x16x32_bf16(ah, bh, accC, 0, 0, 0);
            }
            *(f32x4*)(&Rp2[g][m][lane][0]) = accC;
        }
        __syncthreads();   // bar 4

        // ---- Phase D: fold Rp2; update + simplex projection (wave j); z -> 3-way split ----
        if (wv < BS) {
            const int j = wv, k = lane;
            const int m = k >> 4, p = k & 3, ll = ((k >> 2) & 3) * 16 + j;
            const float r = Rp2[0][m][ll][p] + Rp2[1][m][ll][p]
                          + Rp2[2][m][ll][p] + Rp2[3][m][ll][p];
            const float gz = 2.0f * r - Yh[j][k];
            const float vz = Zs[j][k] - lr * gz;

            // bitonic sort (descending) across 64 lanes
            float sv2 = vz;
            #pragma unroll
            for (int sz = 2; sz <= 64; sz <<= 1) {
                #pragma unroll
                for (int st = sz >> 1; st > 0; st >>= 1) {
                    const float other = __shfl_xor(sv2, st, 64);
                    const bool desc = ((lane & sz) == 0);
                    const bool lower = ((lane & st) == 0);
                    const float mx = fmaxf(sv2, other), mn = fminf(sv2, other);
                    sv2 = (lower == desc) ? mx : mn;
                }
            }
            // inclusive scan -> cumsum - 1
            float css = sv2;
            #pragma unroll
            for (int off = 1; off < 64; off <<= 1) {
                const float nb = __shfl_up(css, off, 64);
                if (lane >= off) css += nb;
            }
            css -= 1.0f;
            const bool cond = (sv2 - css / (float)(lane + 1)) > 0.0f;
            const unsigned long long bal = __ballot(cond);
            const int idx = __popcll(bal) - 1;
            const float cssIdx = __shfl(css, idx, 64);
            const float theta = cssIdx / (float)(idx + 1);
            const float zk = fmaxf(vz - theta, 0.0f);
            Zs[j][k] = zk;
            const unsigned short zh_ = bf16_rne(zk);
            const float zr1 = zk - bf16_tof(zh_);
            const unsigned short zm_ = bf16_rne(zr1);
            const unsigned short zl_ = bf16_rne(zr1 - bf16_tof(zm_));
            Zb_hi[j][k] = zh_; Zb_hi[j + 8][k] = zh_;   // duplicate into cols 8..15
            Zb_md[j][k] = zm_; Zb_md[j + 8][k] = zm_;
            Zb_lo[j][k] = zl_; Zb_lo[j + 8][k] = zl_;
        }
        __syncthreads();   // bar 5
    }

    if (t < BS * NY) {
        const int j = t >> 6, k = t & 63;
        zout[(sc0 + j) * NY + k] = Zs[j][k];
    }
}

extern "C" void kernel_launch(void* const* d_in, const int* in_sizes, int n_in,
                              void* d_out, int out_size, void* d_ws, size_t ws_size,
                              hipStream_t stream) {
    const float* X   = (const float*)d_in[0];
    const float* Y   = (const float*)d_in[1];
    const float* rho = (const float*)d_in[2];
    const float* W   = (const float*)d_in[3];
    const float* b   = (const float*)d_in[4];

    float* out   = (float*)d_out;
    float* zout  = out;                 // Z_star: 2048*64
    float* yhat  = out + NOBS * NY;     // Y_hat:  2048*64

    // workspace: epT_hi | epT_lo | epA_hi | epA_md | epA_lo | epsum  (1.25 MB + 4 B)
    unsigned short* epT_hi = (unsigned short*)d_ws;              // 256 KB
    unsigned short* epT_lo = epT_hi + NY * NOBS;                 // 256 KB
    unsigned short* epA_hi = epT_lo + NY * NOBS;                 // 256 KB
    unsigned short* epA_md = epA_hi + NY * NOBS;                 // 256 KB
    unsigned short* epA_lo = epA_md + NY * NOBS;                 // 256 KB
    float* epsum = (float*)(epA_lo + NY * NOBS);                 // 1 f32

    hipMemsetAsync(epsum, 0, sizeof(float), stream);
    prep_kernel<<<NOBS / 4, 256, 0, stream>>>(X, Y, W, b, yhat, epsum,
                                              epT_hi, epT_lo, epA_hi, epA_md, epA_lo);
    solve_kernel<<<NOBS / BS, NT, 0, stream>>>(yhat, epsum, rho,
                                               epT_hi, epT_lo, epA_hi, epA_md, epA_lo, zout);
}

// Round 10
// 2680.274 us; speedup vs baseline: 1.2259x; 1.2137x over previous
//
#include <hip/hip_runtime.h>

#define NOBS 2048
#define NX   128
#define NY   64
#define BS   8            // scenarios per solver block (256 blocks, 1/CU, all resident)
#define NT   1024         // 16 waves
#define NWAVE (NT / 64)
#define NITER 64

typedef short short8 __attribute__((ext_vector_type(8)));   // 8 bf16 (4 VGPRs)
typedef float f32x4 __attribute__((ext_vector_type(4)));    // MFMA accumulator
typedef unsigned short u16x4 __attribute__((ext_vector_type(4)));

// ---- bf16 split helpers (RNE) ----
__device__ __forceinline__ unsigned short bf16_rne(float x) {
    unsigned u = __float_as_uint(x);
    return (unsigned short)((u + 0x7FFFu + ((u >> 16) & 1u)) >> 16);
}
__device__ __forceinline__ float bf16_tof(unsigned short h) {
    return __uint_as_float(((unsigned)h) << 16);
}

// ---- DPP wave reduction (prep only) ----
template <int CTRL>
__device__ __forceinline__ float dpp_f(float x) {
    return __int_as_float(__builtin_amdgcn_update_dpp(
        0, __float_as_int(x), CTRL, 0xf, 0xf, true));
}
__device__ __forceinline__ float wave_sum64(float v) {
    v += dpp_f<0x111>(v);
    v += dpp_f<0x112>(v);
    v += dpp_f<0x114>(v);
    v += dpp_f<0x118>(v);
    v += dpp_f<0x142>(v);
    v += dpp_f<0x143>(v);   // lane 63 = total
    return v;
}

// ---- Kernel 1: Y_hat = X@W^T + b ; epsum ; ep bf16 3-way split (two layouts) ----
// e = hi + md + lo + r, |r| <~ 2^-24 |e|.  epT uses (hi, md) [2-way], epA uses all 3.
__global__ __launch_bounds__(256) void prep_kernel(
    const float* __restrict__ X, const float* __restrict__ Y,
    const float* __restrict__ W, const float* __restrict__ b,
    float* __restrict__ yhat_out, float* __restrict__ epsum,
    unsigned short* __restrict__ epT_hi, unsigned short* __restrict__ epT_lo,
    unsigned short* __restrict__ epA_hi, unsigned short* __restrict__ epA_md,
    unsigned short* __restrict__ epA_lo)
{
    __shared__ float Xs[4][NX];
    const int t = threadIdx.x;
    const int row0 = blockIdx.x * 4;
    for (int f = t; f < 4 * NX; f += 256)
        Xs[f >> 7][f & 127] = X[(row0 + (f >> 7)) * NX + (f & 127)];
    __syncthreads();

    const int k = t & 63;
    const int r = t >> 6;
    const float4* W4 = reinterpret_cast<const float4*>(W + k * NX);
    const float4* X4 = reinterpret_cast<const float4*>(&Xs[r][0]);
    float acc = 0.f;
    #pragma unroll
    for (int x = 0; x < NX / 4; ++x) {
        float4 wv = W4[x];
        float4 xv = X4[x];
        acc += wv.x * xv.x + wv.y * xv.y + wv.z * xv.z + wv.w * xv.w;
    }
    const float yh = acc + b[k];
    const int i = row0 + r;
    yhat_out[i * NY + k] = yh;
    const float e = Y[i * NY + k] - yh;

    const unsigned short hi = bf16_rne(e);
    const float r1 = e - bf16_tof(hi);
    const unsigned short md = bf16_rne(r1);
    const unsigned short lo = bf16_rne(r1 - bf16_tof(md));
    // Phase C A-frag (rows = k, K = i):  A[row=lane&15][kk=8*(lane>>4)+d]
    {
        const int m  = k >> 4;
        const int q  = i >> 5;
        const int lc = (k & 15) + 16 * ((i >> 3) & 3);
        const int d  = i & 7;
        const int idx = ((m * 64 + q) * 64 + lc) * 8 + d;
        epT_hi[idx] = hi;
        epT_lo[idx] = md;
    }
    // Phase A A-frag (rows = i, K = k)
    {
        const int m  = i >> 4;
        const int q  = k >> 5;
        const int lc = (i & 15) + 16 * ((k >> 3) & 3);
        const int d  = k & 7;
        const int idx = ((m * 2 + q) * 64 + lc) * 8 + d;
        epA_hi[idx] = hi;
        epA_md[idx] = md;
        epA_lo[idx] = lo;
    }

    float se = wave_sum64(e);
    if ((t & 63) == 63) atomicAdd(epsum, se);
}

// ---- Kernel 2: batched projected-subgradient DRO solve ----
// Phase A on MFMA (3-way split, 6 terms, two passes); Phase C on MFMA (2-way,
// 3 terms). 5 barriers/iter.
// Anti-spill design (R7-R9 lesson: 7.3 GB scratch FETCH at 2.4 TB/s was the
// whole runtime): (a) NO second launch_bounds arg — any value pinned the
// allocator at 64 VGPRs (R3 precedent: plain bound -> 84 VGPRs, no spill);
// (b) the only large cross-barrier state, sv_[4][4], is stashed in LDS
// (Sbuf, per-thread-exclusive slots, contiguous b128, no sync needed).
__global__ __launch_bounds__(NT) void solve_kernel(
    const float* __restrict__ yhat, const float* __restrict__ epsum,
    const float* __restrict__ rho_p,
    const unsigned short* __restrict__ epT_hi, const unsigned short* __restrict__ epT_lo,
    const unsigned short* __restrict__ epA_hi, const unsigned short* __restrict__ epA_md,
    const unsigned short* __restrict__ epA_lo,
    float* __restrict__ zout)
{
    __shared__ float Zs[BS][NY];                 // 2 KB
    __shared__ float Yh[BS][NY];                 // 2 KB
    __shared__ unsigned short VT_hi[BS][2056];   // 32.1 KB
    __shared__ unsigned short VT_lo[BS][2056];   // 32.1 KB
    __shared__ __align__(16) unsigned short Zb_hi[16][72];  // 2.25 KB (cols 8..15 dup)
    __shared__ __align__(16) unsigned short Zb_md[16][72];  // 2.25 KB
    __shared__ __align__(16) unsigned short Zb_lo[16][72];  // 2.25 KB
    __shared__ float Rp2[4][4][64][4];           // 16 KB  [g][m][lane][reg]
    __shared__ float4 Sbuf[NWAVE][4][64];        // 64 KB  per-thread s stash (cross-barrier)
    __shared__ float redM[NWAVE][BS];            // per-wave umax partials
    __shared__ float red2[NWAVE][BS][4];         // per-wave {pa,pe,pas,pes}
    __shared__ float cS[16], lamS[16];           // cols 8..15 dup
    __shared__ __align__(16) unsigned short zb[8];

    const int t = threadIdx.x;
    const int lane = t & 63;
    const int wv = t >> 6;
    const int jb = lane & 15;      // MFMA column
    const int h  = lane >> 4;      // frag k-chunk / row-group
    const int j8 = jb & 7;         // actual scenario
    const bool hiHalf = (jb >= 8);
    const int sc0 = blockIdx.x * BS;
    const float rho = rho_p[0];

    if (t < BS * NY) {
        const int j = t >> 6, k = t & 63;
        Yh[j][k] = yhat[(sc0 + j) * NY + k];
        Zs[j][k] = 1.0f / 64.0f;
    }
    {   // z0 = 1/64 exact in bf16 (power of two) -> md = lo = 0
        const int j = t >> 6, k = t & 63;
        Zb_hi[j][k] = bf16_rne(1.0f / 64.0f);
        Zb_md[j][k] = 0;
        Zb_lo[j][k] = 0;
    }
    if (t < 16) {
        cS[t] = epsum[0] * (1.0f / 131072.0f);  // mean(ep) == mean(ep @ z0)
        lamS[t] = 1.0f;
    }
    if (t < 8) zb[t] = 0;
    __syncthreads();

    for (int it = 0; it < NITER; ++it) {
        const float lr = 0.05f / sqrtf((float)it + 1.0f);

        const float cR = cS[jb];
        const float lm = lamS[jb];

        // ---- Phase A: S = ep.z - c via MFMA, 6-term 3-way split, two passes ----
        // pass 0: m-tiles 0..3 (lo-half lanes extract); pass 1: tiles 4..7 (hi-half).
        float sv_[4][4];
        #pragma unroll
        for (int pass = 0; pass < 2; ++pass) {
            f32x4 acc[4];
            #pragma unroll
            for (int n = 0; n < 4; ++n) acc[n] = (f32x4){0.f, 0.f, 0.f, 0.f};
            #pragma unroll
            for (int q = 0; q < 2; ++q) {
                const short8 zh = *(const short8*)&Zb_hi[jb][(q << 5) + (h << 3)];
                const short8 zm = *(const short8*)&Zb_md[jb][(q << 5) + (h << 3)];
                const short8 zl = *(const short8*)&Zb_lo[jb][(q << 5) + (h << 3)];
                #pragma unroll
                for (int n = 0; n < 4; ++n) {
                    const int mi = pass * 4 + n;
                    const int aoff = ((((wv << 3) + mi) * 2 + q) * 64 + lane) * 8;
                    const short8 ah = *(const short8*)(epA_hi + aoff);
                    const short8 am = *(const short8*)(epA_md + aoff);
                    const short8 al = *(const short8*)(epA_lo + aoff);
                    acc[n] = __builtin_amdgcn_mfma_f32_16x16x32_bf16(al, zh, acc[n], 0, 0, 0); // lH
                    acc[n] = __builtin_amdgcn_mfma_f32_16x16x32_bf16(ah, zl, acc[n], 0, 0, 0); // hL
                    acc[n] = __builtin_amdgcn_mfma_f32_16x16x32_bf16(am, zm, acc[n], 0, 0, 0); // mM
                    acc[n] = __builtin_amdgcn_mfma_f32_16x16x32_bf16(am, zh, acc[n], 0, 0, 0); // mH
                    acc[n] = __builtin_amdgcn_mfma_f32_16x16x32_bf16(ah, zm, acc[n], 0, 0, 0); // hM
                    acc[n] = __builtin_amdgcn_mfma_f32_16x16x32_bf16(ah, zh, acc[n], 0, 0, 0); // hH
                }
            }
            const bool take = (hiHalf == (pass == 1));
            #pragma unroll
            for (int n = 0; n < 4; ++n)
                #pragma unroll
                for (int p = 0; p < 4; ++p)
                    if (take) sv_[n][p] = acc[n][p] - cR;  // s for i = 16*(8wv+4*pass+n)+4h+p
            __builtin_amdgcn_sched_barrier(0);   // keep passes separate (cap acc liveness)
        }

        // ---- stash s in LDS (per-thread slot; read back in B2/B4 — frees 16 VGPRs) ----
        #pragma unroll
        for (int n = 0; n < 4; ++n)
            Sbuf[wv][n][lane] = make_float4(sv_[n][0], sv_[n][1], sv_[n][2], sv_[n][3]);

        // ---- Phase B1: per-wave umax (in-lane 16 -> xor 8/16/32); u = s*s ----
        float pm = sv_[0][0] * sv_[0][0];
        #pragma unroll
        for (int n = 0; n < 4; ++n)
            #pragma unroll
            for (int p = 0; p < 4; ++p) pm = fmaxf(pm, sv_[n][p] * sv_[n][p]);
        pm = fmaxf(pm, __shfl_xor(pm, 8, 64));
        pm = fmaxf(pm, __shfl_xor(pm, 16, 64));
        pm = fmaxf(pm, __shfl_xor(pm, 32, 64));
        if (lane < 8) redM[wv][lane] = pm;
        __syncthreads();   // bar 1

        // ---- umax fold (all lanes) ----
        float um = redM[0][j8];
        #pragma unroll
        for (int w = 1; w < NWAVE; ++w) um = fmaxf(um, redM[w][j8]);

        // ---- Phase B2: sums of a, eq, a*s, eq*s (JAX balanced-tie semantics) ----
        float pa = 0.f, pe = 0.f, pas = 0.f, pes = 0.f;
        #pragma unroll
        for (int n = 0; n < 4; ++n) {
            const float4 s4 = Sbuf[wv][n][lane];
            const float sarr[4] = {s4.x, s4.y, s4.z, s4.w};
            #pragma unroll
            for (int p = 0; p < 4; ++p) {
                const float ss = sarr[p], u = ss * ss;
                const float x = (u - um) + lm;
                const float a = (x > -lm) ? 1.0f : ((x == -lm) ? 0.5f : 0.0f);
                const float e = (u == um) ? 1.0f : 0.0f;
                pa += a; pe += e; pas += a * ss; pes += e * ss;
            }
        }
        pa  += __shfl_xor(pa, 8, 64);  pa  += __shfl_xor(pa, 16, 64);  pa  += __shfl_xor(pa, 32, 64);
        pe  += __shfl_xor(pe, 8, 64);  pe  += __shfl_xor(pe, 16, 64);  pe  += __shfl_xor(pe, 32, 64);
        pas += __shfl_xor(pas, 8, 64); pas += __shfl_xor(pas, 16, 64); pas += __shfl_xor(pas, 32, 64);
        pes += __shfl_xor(pes, 8, 64); pes += __shfl_xor(pes, 16, 64); pes += __shfl_xor(pes, 32, 64);
        if (lane < 8) {
            f32x4 r4 = {pa, pe, pas, pes};
            *(f32x4*)&red2[wv][lane][0] = r4;
        }
        __syncthreads();   // bar 2

        // ---- sum fold (all lanes, b128 broadcast reads); c/lam update by wave 0 ----
        float sA = 0.f, sE = 0.f, sAS = 0.f, sES = 0.f;
        #pragma unroll
        for (int w = 0; w < NWAVE; ++w) {
            const f32x4 rr = *(const f32x4*)&red2[w][j8][0];
            sA += rr[0]; sE += rr[1]; sAS += rr[2]; sES += rr[3];
        }
        const float abar = sA * (1.0f / (float)NOBS);
        const float wA = (1.0f - abar) / sE;      // argmax weight / tie count
        const float gc = -2.0f * (sAS * (1.0f / (float)NOBS) + wA * sES);
        const float glam = (rho - 2.0f) + 2.0f * abar;
        if (wv == 0 && lane < 16) {               // consumed next iteration (after bar 5)
            cS[lane] = cS[lane] - lr * gc;
            lamS[lane] = fmaxf(lamS[lane] - lr * glam, 0.0f);
        }

        // ---- Phase B4: v = (a/n + eq*wA) * s -> bf16 hi/lo packed b64 into VT ----
        #pragma unroll
        for (int n = 0; n < 4; ++n) {
            const float4 s4 = Sbuf[wv][n][lane];
            const float sarr[4] = {s4.x, s4.y, s4.z, s4.w};
            u16x4 vh4, vl4;
            #pragma unroll
            for (int p = 0; p < 4; ++p) {
                const float ss = sarr[p], u = ss * ss;
                const float x = (u - um) + lm;
                const float a = (x > -lm) ? 1.0f : ((x == -lm) ? 0.5f : 0.0f);
                const float e = (u == um) ? 1.0f : 0.0f;
                const float vv = (a * (1.0f / (float)NOBS) + e * wA) * ss;
                const unsigned short vhh = bf16_rne(vv);
                vh4[p] = vhh;
                vl4[p] = bf16_rne(vv - bf16_tof(vhh));
            }
            const int ii = ((wv << 3) + (hiHalf ? 4 : 0) + n) * 16 + (h << 2);
            *(u16x4*)&VT_hi[j8][ii] = vh4;
            *(u16x4*)&VT_lo[j8][ii] = vl4;
        }
        __syncthreads();   // bar 3

        // ---- Phase C: r = ep^T v via MFMA, 3-term 2-way split (R5-proven) ----
        {
            const int m = wv & 3;
            const int g = wv >> 2;
            f32x4 accC = {0.f, 0.f, 0.f, 0.f};
            #pragma unroll 4
            for (int qq = 0; qq < 16; ++qq) {
                const int q = g * 16 + qq;
                const int aoff = ((m * 64 + q) * 64 + lane) * 8;
                const short8 ah = *(const short8*)(epT_hi + aoff);
                const short8 al = *(const short8*)(epT_lo + aoff);
                const unsigned short* vh = (!hiHalf) ? &VT_hi[jb][(q << 5) + (h << 3)] : zb;
                const unsigned short* vl = (!hiHalf) ? &VT_lo[jb][(q << 5) + (h << 3)] : zb;
                const short8 bh = *(const short8*)vh;
                const short8 bl = *(const short8*)vl;
                accC = __builtin_amdgcn_mfma_f32_16x16x32_bf16(al, bh, accC, 0, 0, 0);
                accC = __builtin_amdgcn_mfma_f32_16x16x32_bf16(ah, bl, accC, 0, 0, 0);
                accC = __builtin_amdgcn_mfma_f32_16x16x32_bf16(ah, bh, accC, 0, 0, 0);
            }
            *(f32x4*)(&Rp2[g][m][lane][0]) = accC;
        }
        __syncthreads();   // bar 4

        // ---- Phase D: fold Rp2; update + simplex projection (wave j); z -> 3-way split ----
        if (wv < BS) {
            const int j = wv, k = lane;
            const int m = k >> 4, p = k & 3, ll = ((k >> 2) & 3) * 16 + j;
            const float r = Rp2[0][m][ll][p] + Rp2[1][m][ll][p]
                          + Rp2[2][m][ll][p] + Rp2[3][m][ll][p];
            const float gz = 2.0f * r - Yh[j][k];
            const float vz = Zs[j][k] - lr * gz;

            // bitonic sort (descending) across 64 lanes
            float sv2 = vz;
            #pragma unroll
            for (int sz = 2; sz <= 64; sz <<= 1) {
                #pragma unroll
                for (int st = sz >> 1; st > 0; st >>= 1) {
                    const float other = __shfl_xor(sv2, st, 64);
                    const bool desc = ((lane & sz) == 0);
                    const bool lower = ((lane & st) == 0);
                    const float mx = fmaxf(sv2, other), mn = fminf(sv2, other);
                    sv2 = (lower == desc) ? mx : mn;
                }
            }
            // inclusive scan -> cumsum - 1
            float css = sv2;
            #pragma unroll
            for (int off = 1; off < 64; off <<= 1) {
                const float nb = __shfl_up(css, off, 64);
                if (lane >= off) css += nb;
            }
            css -= 1.0f;
            const bool cond = (sv2 - css / (float)(lane + 1)) > 0.0f;
            const unsigned long long bal = __ballot(cond);
            const int idx = __popcll(bal) - 1;
            const float cssIdx = __shfl(css, idx, 64);
            const float theta = cssIdx / (float)(idx + 1);
            const float zk = fmaxf(vz - theta, 0.0f);
            Zs[j][k] = zk;
            const unsigned short zh_ = bf16_rne(zk);
            const float zr1 = zk - bf16_tof(zh_);
            const unsigned short zm_ = bf16_rne(zr1);
            const unsigned short zl_ = bf16_rne(zr1 - bf16_tof(zm_));
            Zb_hi[j][k] = zh_; Zb_hi[j + 8][k] = zh_;   // duplicate into cols 8..15
            Zb_md[j][k] = zm_; Zb_md[j + 8][k] = zm_;
            Zb_lo[j][k] = zl_; Zb_lo[j + 8][k] = zl_;
        }
        __syncthreads();   // bar 5
    }

    if (t < BS * NY) {
        const int j = t >> 6, k = t & 63;
        zout[(sc0 + j) * NY + k] = Zs[j][k];
    }
}

extern "C" void kernel_launch(void* const* d_in, const int* in_sizes, int n_in,
                              void* d_out, int out_size, void* d_ws, size_t ws_size,
                              hipStream_t stream) {
    const float* X   = (const float*)d_in[0];
    const float* Y   = (const float*)d_in[1];
    const float* rho = (const float*)d_in[2];
    const float* W   = (const float*)d_in[3];
    const float* b   = (const float*)d_in[4];

    float* out   = (float*)d_out;
    float* zout  = out;                 // Z_star: 2048*64
    float* yhat  = out + NOBS * NY;     // Y_hat:  2048*64

    // workspace: epT_hi | epT_lo | epA_hi | epA_md | epA_lo | epsum  (1.25 MB + 4 B)
    unsigned short* epT_hi = (unsigned short*)d_ws;              // 256 KB
    unsigned short* epT_lo = epT_hi + NY * NOBS;                 // 256 KB
    unsigned short* epA_hi = epT_lo + NY * NOBS;                 // 256 KB
    unsigned short* epA_md = epA_hi + NY * NOBS;                 // 256 KB
    unsigned short* epA_lo = epA_md + NY * NOBS;                 // 256 KB
    float* epsum = (float*)(epA_lo + NY * NOBS);                 // 1 f32

    hipMemsetAsync(epsum, 0, sizeof(float), stream);
    prep_kernel<<<NOBS / 4, 256, 0, stream>>>(X, Y, W, b, yhat, epsum,
                                              epT_hi, epT_lo, epA_hi, epA_md, epA_lo);
    solve_kernel<<<NOBS / BS, NT, 0, stream>>>(yhat, epsum, rho,
                                               epT_hi, epT_lo, epA_hi, epA_md, epA_lo, zout);
}

// Round 11
// 2475.323 us; speedup vs baseline: 1.3274x; 1.0828x over previous
//
#include <hip/hip_runtime.h>

#define NOBS 2048
#define NX   128
#define NY   64
#define BS   8            // scenarios per solver block (256 blocks, 1/CU, all resident)
#define NT   1024         // 16 waves
#define NWAVE (NT / 64)
#define NITER 64

typedef short short8 __attribute__((ext_vector_type(8)));   // 8 bf16 (4 VGPRs)
typedef float f32x4 __attribute__((ext_vector_type(4)));    // MFMA accumulator
typedef unsigned short u16x4 __attribute__((ext_vector_type(4)));

// ---- bf16 split helpers (RNE) ----
__device__ __forceinline__ unsigned short bf16_rne(float x) {
    unsigned u = __float_as_uint(x);
    return (unsigned short)((u + 0x7FFFu + ((u >> 16) & 1u)) >> 16);
}
__device__ __forceinline__ float bf16_tof(unsigned short h) {
    return __uint_as_float(((unsigned)h) << 16);
}

// ---- DPP wave reduction (prep only) ----
template <int CTRL>
__device__ __forceinline__ float dpp_f(float x) {
    return __int_as_float(__builtin_amdgcn_update_dpp(
        0, __float_as_int(x), CTRL, 0xf, 0xf, true));
}
__device__ __forceinline__ float wave_sum64(float v) {
    v += dpp_f<0x111>(v);
    v += dpp_f<0x112>(v);
    v += dpp_f<0x114>(v);
    v += dpp_f<0x118>(v);
    v += dpp_f<0x142>(v);
    v += dpp_f<0x143>(v);   // lane 63 = total
    return v;
}

// ---- Kernel 1: Y_hat = X@W^T + b ; epsum ; ep bf16 3-way split (two layouts) ----
// e = hi + md + lo + r, |r| <~ 2^-24 |e|.  epT uses (hi, md) [2-way], epA uses all 3.
__global__ __launch_bounds__(256) void prep_kernel(
    const float* __restrict__ X, const float* __restrict__ Y,
    const float* __restrict__ W, const float* __restrict__ b,
    float* __restrict__ yhat_out, float* __restrict__ epsum,
    unsigned short* __restrict__ epT_hi, unsigned short* __restrict__ epT_lo,
    unsigned short* __restrict__ epA_hi, unsigned short* __restrict__ epA_md,
    unsigned short* __restrict__ epA_lo)
{
    __shared__ float Xs[4][NX];
    const int t = threadIdx.x;
    const int row0 = blockIdx.x * 4;
    for (int f = t; f < 4 * NX; f += 256)
        Xs[f >> 7][f & 127] = X[(row0 + (f >> 7)) * NX + (f & 127)];
    __syncthreads();

    const int k = t & 63;
    const int r = t >> 6;
    const float4* W4 = reinterpret_cast<const float4*>(W + k * NX);
    const float4* X4 = reinterpret_cast<const float4*>(&Xs[r][0]);
    float acc = 0.f;
    #pragma unroll
    for (int x = 0; x < NX / 4; ++x) {
        float4 wv = W4[x];
        float4 xv = X4[x];
        acc += wv.x * xv.x + wv.y * xv.y + wv.z * xv.z + wv.w * xv.w;
    }
    const float yh = acc + b[k];
    const int i = row0 + r;
    yhat_out[i * NY + k] = yh;
    const float e = Y[i * NY + k] - yh;

    const unsigned short hi = bf16_rne(e);
    const float r1 = e - bf16_tof(hi);
    const unsigned short md = bf16_rne(r1);
    const unsigned short lo = bf16_rne(r1 - bf16_tof(md));
    // Phase C A-frag (rows = k, K = i):  A[row=lane&15][kk=8*(lane>>4)+d]
    {
        const int m  = k >> 4;
        const int q  = i >> 5;
        const int lc = (k & 15) + 16 * ((i >> 3) & 3);
        const int d  = i & 7;
        const int idx = ((m * 64 + q) * 64 + lc) * 8 + d;
        epT_hi[idx] = hi;
        epT_lo[idx] = md;
    }
    // Phase A A-frag (rows = i, K = k)
    {
        const int m  = i >> 4;
        const int q  = k >> 5;
        const int lc = (i & 15) + 16 * ((k >> 3) & 3);
        const int d  = k & 7;
        const int idx = ((m * 2 + q) * 64 + lc) * 8 + d;
        epA_hi[idx] = hi;
        epA_md[idx] = md;
        epA_lo[idx] = lo;
    }

    float se = wave_sum64(e);
    if ((t & 63) == 63) atomicAdd(epsum, se);
}

// ---- Kernel 2: batched projected-subgradient DRO solve ----
// Phase A on MFMA (3-way split, 6 terms, two passes); Phase C on MFMA (2-way,
// 3 terms). 5 barriers/iter.
// Register story (R7-R10): the allocator pins 64 VGPRs chasing 8-waves/EU
// occupancy that the 161-KB LDS footprint makes impossible (1 block/CU
// = 4 waves/EU), and spills ~6 GB/dispatch of scratch traffic that thrashes
// L2 (R5's no-spill build: FETCH 9.6 MB; R10: 6.2 GB). Fix: amdgpu_waves_per_eu
// with MAX=4 — tells the allocator "exactly 4 waves/EU", unlocking the full
// 512/4 = 128-VGPR budget for precisely the occupancy we already have.
__global__ __launch_bounds__(NT)
__attribute__((amdgpu_waves_per_eu(4, 4)))
void solve_kernel(
    const float* __restrict__ yhat, const float* __restrict__ epsum,
    const float* __restrict__ rho_p,
    const unsigned short* __restrict__ epT_hi, const unsigned short* __restrict__ epT_lo,
    const unsigned short* __restrict__ epA_hi, const unsigned short* __restrict__ epA_md,
    const unsigned short* __restrict__ epA_lo,
    float* __restrict__ zout)
{
    __shared__ float Zs[BS][NY];                 // 2 KB
    __shared__ float Yh[BS][NY];                 // 2 KB
    __shared__ unsigned short VT_hi[BS][2056];   // 32.1 KB
    __shared__ unsigned short VT_lo[BS][2056];   // 32.1 KB
    __shared__ __align__(16) unsigned short Zb_hi[16][72];  // 2.25 KB (cols 8..15 dup)
    __shared__ __align__(16) unsigned short Zb_md[16][72];  // 2.25 KB
    __shared__ __align__(16) unsigned short Zb_lo[16][72];  // 2.25 KB
    __shared__ float Rp2[4][4][64][4];           // 16 KB  [g][m][lane][reg]
    __shared__ float4 Sbuf[NWAVE][4][64];        // 64 KB  per-thread s stash (cross-barrier)
    __shared__ float redM[NWAVE][BS];            // per-wave umax partials
    __shared__ float red2[NWAVE][BS][4];         // per-wave {pa,pe,pas,pes}
    __shared__ float cS[16], lamS[16];           // cols 8..15 dup
    __shared__ __align__(16) unsigned short zb[8];

    const int t = threadIdx.x;
    const int lane = t & 63;
    const int wv = t >> 6;
    const int jb = lane & 15;      // MFMA column
    const int h  = lane >> 4;      // frag k-chunk / row-group
    const int j8 = jb & 7;         // actual scenario
    const bool hiHalf = (jb >= 8);
    const int sc0 = blockIdx.x * BS;
    const float rho = rho_p[0];

    if (t < BS * NY) {
        const int j = t >> 6, k = t & 63;
        Yh[j][k] = yhat[(sc0 + j) * NY + k];
        Zs[j][k] = 1.0f / 64.0f;
    }
    {   // z0 = 1/64 exact in bf16 (power of two) -> md = lo = 0
        const int j = t >> 6, k = t & 63;
        Zb_hi[j][k] = bf16_rne(1.0f / 64.0f);
        Zb_md[j][k] = 0;
        Zb_lo[j][k] = 0;
    }
    if (t < 16) {
        cS[t] = epsum[0] * (1.0f / 131072.0f);  // mean(ep) == mean(ep @ z0)
        lamS[t] = 1.0f;
    }
    if (t < 8) zb[t] = 0;
    __syncthreads();

    for (int it = 0; it < NITER; ++it) {
        const float lr = 0.05f / sqrtf((float)it + 1.0f);

        const float cR = cS[jb];
        const float lm = lamS[jb];

        // ---- Phase A: S = ep.z - c via MFMA, 6-term 3-way split, two passes ----
        // pass 0: m-tiles 0..3 (lo-half lanes extract); pass 1: tiles 4..7 (hi-half).
        float sv_[4][4];
        #pragma unroll
        for (int pass = 0; pass < 2; ++pass) {
            f32x4 acc[4];
            #pragma unroll
            for (int n = 0; n < 4; ++n) acc[n] = (f32x4){0.f, 0.f, 0.f, 0.f};
            #pragma unroll
            for (int q = 0; q < 2; ++q) {
                const short8 zh = *(const short8*)&Zb_hi[jb][(q << 5) + (h << 3)];
                const short8 zm = *(const short8*)&Zb_md[jb][(q << 5) + (h << 3)];
                const short8 zl = *(const short8*)&Zb_lo[jb][(q << 5) + (h << 3)];
                #pragma unroll
                for (int n = 0; n < 4; ++n) {
                    const int mi = pass * 4 + n;
                    const int aoff = ((((wv << 3) + mi) * 2 + q) * 64 + lane) * 8;
                    const short8 ah = *(const short8*)(epA_hi + aoff);
                    const short8 am = *(const short8*)(epA_md + aoff);
                    const short8 al = *(const short8*)(epA_lo + aoff);
                    acc[n] = __builtin_amdgcn_mfma_f32_16x16x32_bf16(al, zh, acc[n], 0, 0, 0); // lH
                    acc[n] = __builtin_amdgcn_mfma_f32_16x16x32_bf16(ah, zl, acc[n], 0, 0, 0); // hL
                    acc[n] = __builtin_amdgcn_mfma_f32_16x16x32_bf16(am, zm, acc[n], 0, 0, 0); // mM
                    acc[n] = __builtin_amdgcn_mfma_f32_16x16x32_bf16(am, zh, acc[n], 0, 0, 0); // mH
                    acc[n] = __builtin_amdgcn_mfma_f32_16x16x32_bf16(ah, zm, acc[n], 0, 0, 0); // hM
                    acc[n] = __builtin_amdgcn_mfma_f32_16x16x32_bf16(ah, zh, acc[n], 0, 0, 0); // hH
                }
            }
            const bool take = (hiHalf == (pass == 1));
            #pragma unroll
            for (int n = 0; n < 4; ++n)
                #pragma unroll
                for (int p = 0; p < 4; ++p)
                    if (take) sv_[n][p] = acc[n][p] - cR;  // s for i = 16*(8wv+4*pass+n)+4h+p
            __builtin_amdgcn_sched_barrier(0);   // keep passes separate (cap acc liveness)
        }

        // ---- stash s in LDS (per-thread slot; read back in B2/B4 — frees 16 VGPRs) ----
        #pragma unroll
        for (int n = 0; n < 4; ++n)
            Sbuf[wv][n][lane] = make_float4(sv_[n][0], sv_[n][1], sv_[n][2], sv_[n][3]);

        // ---- Phase B1: per-wave umax (in-lane 16 -> xor 8/16/32); u = s*s ----
        float pm = sv_[0][0] * sv_[0][0];
        #pragma unroll
        for (int n = 0; n < 4; ++n)
            #pragma unroll
            for (int p = 0; p < 4; ++p) pm = fmaxf(pm, sv_[n][p] * sv_[n][p]);
        pm = fmaxf(pm, __shfl_xor(pm, 8, 64));
        pm = fmaxf(pm, __shfl_xor(pm, 16, 64));
        pm = fmaxf(pm, __shfl_xor(pm, 32, 64));
        if (lane < 8) redM[wv][lane] = pm;
        __syncthreads();   // bar 1

        // ---- umax fold (all lanes) ----
        float um = redM[0][j8];
        #pragma unroll
        for (int w = 1; w < NWAVE; ++w) um = fmaxf(um, redM[w][j8]);

        // ---- Phase B2: sums of a, eq, a*s, eq*s (JAX balanced-tie semantics) ----
        float pa = 0.f, pe = 0.f, pas = 0.f, pes = 0.f;
        #pragma unroll
        for (int n = 0; n < 4; ++n) {
            const float4 s4 = Sbuf[wv][n][lane];
            const float sarr[4] = {s4.x, s4.y, s4.z, s4.w};
            #pragma unroll
            for (int p = 0; p < 4; ++p) {
                const float ss = sarr[p], u = ss * ss;
                const float x = (u - um) + lm;
                const float a = (x > -lm) ? 1.0f : ((x == -lm) ? 0.5f : 0.0f);
                const float e = (u == um) ? 1.0f : 0.0f;
                pa += a; pe += e; pas += a * ss; pes += e * ss;
            }
        }
        pa  += __shfl_xor(pa, 8, 64);  pa  += __shfl_xor(pa, 16, 64);  pa  += __shfl_xor(pa, 32, 64);
        pe  += __shfl_xor(pe, 8, 64);  pe  += __shfl_xor(pe, 16, 64);  pe  += __shfl_xor(pe, 32, 64);
        pas += __shfl_xor(pas, 8, 64); pas += __shfl_xor(pas, 16, 64); pas += __shfl_xor(pas, 32, 64);
        pes += __shfl_xor(pes, 8, 64); pes += __shfl_xor(pes, 16, 64); pes += __shfl_xor(pes, 32, 64);
        if (lane < 8) {
            f32x4 r4 = {pa, pe, pas, pes};
            *(f32x4*)&red2[wv][lane][0] = r4;
        }
        __syncthreads();   // bar 2

        // ---- sum fold (all lanes, b128 broadcast reads); c/lam update by wave 0 ----
        float sA = 0.f, sE = 0.f, sAS = 0.f, sES = 0.f;
        #pragma unroll
        for (int w = 0; w < NWAVE; ++w) {
            const f32x4 rr = *(const f32x4*)&red2[w][j8][0];
            sA += rr[0]; sE += rr[1]; sAS += rr[2]; sES += rr[3];
        }
        const float abar = sA * (1.0f / (float)NOBS);
        const float wA = (1.0f - abar) / sE;      // argmax weight / tie count
        const float gc = -2.0f * (sAS * (1.0f / (float)NOBS) + wA * sES);
        const float glam = (rho - 2.0f) + 2.0f * abar;
        if (wv == 0 && lane < 16) {               // consumed next iteration (after bar 5)
            cS[lane] = cS[lane] - lr * gc;
            lamS[lane] = fmaxf(lamS[lane] - lr * glam, 0.0f);
        }

        // ---- Phase B4: v = (a/n + eq*wA) * s -> bf16 hi/lo packed b64 into VT ----
        #pragma unroll
        for (int n = 0; n < 4; ++n) {
            const float4 s4 = Sbuf[wv][n][lane];
            const float sarr[4] = {s4.x, s4.y, s4.z, s4.w};
            u16x4 vh4, vl4;
            #pragma unroll
            for (int p = 0; p < 4; ++p) {
                const float ss = sarr[p], u = ss * ss;
                const float x = (u - um) + lm;
                const float a = (x > -lm) ? 1.0f : ((x == -lm) ? 0.5f : 0.0f);
                const float e = (u == um) ? 1.0f : 0.0f;
                const float vv = (a * (1.0f / (float)NOBS) + e * wA) * ss;
                const unsigned short vhh = bf16_rne(vv);
                vh4[p] = vhh;
                vl4[p] = bf16_rne(vv - bf16_tof(vhh));
            }
            const int ii = ((wv << 3) + (hiHalf ? 4 : 0) + n) * 16 + (h << 2);
            *(u16x4*)&VT_hi[j8][ii] = vh4;
            *(u16x4*)&VT_lo[j8][ii] = vl4;
        }
        __syncthreads();   // bar 3

        // ---- Phase C: r = ep^T v via MFMA, 3-term 2-way split (R5-proven) ----
        {
            const int m = wv & 3;
            const int g = wv >> 2;
            f32x4 accC = {0.f, 0.f, 0.f, 0.f};
            #pragma unroll 4
            for (int qq = 0; qq < 16; ++qq) {
                const int q = g * 16 + qq;
                const int aoff = ((m * 64 + q) * 64 + lane) * 8;
                const short8 ah = *(const short8*)(epT_hi + aoff);
                const short8 al = *(const short8*)(epT_lo + aoff);
                const unsigned short* vh = (!hiHalf) ? &VT_hi[jb][(q << 5) + (h << 3)] : zb;
                const unsigned short* vl = (!hiHalf) ? &VT_lo[jb][(q << 5) + (h << 3)] : zb;
                const short8 bh = *(const short8*)vh;
                const short8 bl = *(const short8*)vl;
                accC = __builtin_amdgcn_mfma_f32_16x16x32_bf16(al, bh, accC, 0, 0, 0);
                accC = __builtin_amdgcn_mfma_f32_16x16x32_bf16(ah, bl, accC, 0, 0, 0);
                accC = __builtin_amdgcn_mfma_f32_16x16x32_bf16(ah, bh, accC, 0, 0, 0);
            }
            *(f32x4*)(&Rp2[g][m][lane][0]) = accC;
        }
        __syncthreads();   // bar 4

        // ---- Phase D: fold Rp2; update + simplex projection (wave j); z -> 3-way split ----
        if (wv < BS) {
            const int j = wv, k = lane;
            const int m = k >> 4, p = k & 3, ll = ((k >> 2) & 3) * 16 + j;
            const float r = Rp2[0][m][ll][p] + Rp2[1][m][ll][p]
                          + Rp2[2][m][ll][p] + Rp2[3][m][ll][p];
            const float gz = 2.0f * r - Yh[j][k];
            const float vz = Zs[j][k] - lr * gz;

            // bitonic sort (descending) across 64 lanes
            float sv2 = vz;
            #pragma unroll
            for (int sz = 2; sz <= 64; sz <<= 1) {
                #pragma unroll
                for (int st = sz >> 1; st > 0; st >>= 1) {
                    const float other = __shfl_xor(sv2, st, 64);
                    const bool desc = ((lane & sz) == 0);
                    const bool lower = ((lane & st) == 0);
                    const float mx = fmaxf(sv2, other), mn = fminf(sv2, other);
                    sv2 = (lower == desc) ? mx : mn;
                }
            }
            // inclusive scan -> cumsum - 1
            float css = sv2;
            #pragma unroll
            for (int off = 1; off < 64; off <<= 1) {
                const float nb = __shfl_up(css, off, 64);
                if (lane >= off) css += nb;
            }
            css -= 1.0f;
            const bool cond = (sv2 - css / (float)(lane + 1)) > 0.0f;
            const unsigned long long bal = __ballot(cond);
            const int idx = __popcll(bal) - 1;
            const float cssIdx = __shfl(css, idx, 64);
            const float theta = cssIdx / (float)(idx + 1);
            const float zk = fmaxf(vz - theta, 0.0f);
            Zs[j][k] = zk;
            const unsigned short zh_ = bf16_rne(zk);
            const float zr1 = zk - bf16_tof(zh_);
            const unsigned short zm_ = bf16_rne(zr1);
            const unsigned short zl_ = bf16_rne(zr1 - bf16_tof(zm_));
            Zb_hi[j][k] = zh_; Zb_hi[j + 8][k] = zh_;   // duplicate into cols 8..15
            Zb_md[j][k] = zm_; Zb_md[j + 8][k] = zm_;
            Zb_lo[j][k] = zl_; Zb_lo[j + 8][k] = zl_;
        }
        __syncthreads();   // bar 5
    }

    if (t < BS * NY) {
        const int j = t >> 6, k = t & 63;
        zout[(sc0 + j) * NY + k] = Zs[j][k];
    }
}

extern "C" void kernel_launch(void* const* d_in, const int* in_sizes, int n_in,
                              void* d_out, int out_size, void* d_ws, size_t ws_size,
                              hipStream_t stream) {
    const float* X   = (const float*)d_in[0];
    const float* Y   = (const float*)d_in[1];
    const float* rho = (const float*)d_in[2];
    const float* W   = (const float*)d_in[3];
    const float* b   = (const float*)d_in[4];

    float* out   = (float*)d_out;
    float* zout  = out;                 // Z_star: 2048*64
    float* yhat  = out + NOBS * NY;     // Y_hat:  2048*64

    // workspace: epT_hi | epT_lo | epA_hi | epA_md | epA_lo | epsum  (1.25 MB + 4 B)
    unsigned short* epT_hi = (unsigned short*)d_ws;              // 256 KB
    unsigned short* epT_lo = epT_hi + NY * NOBS;                 // 256 KB
    unsigned short* epA_hi = epT_lo + NY * NOBS;                 // 256 KB
    unsigned short* epA_md = epA_hi + NY * NOBS;                 // 256 KB
    unsigned short* epA_lo = epA_md + NY * NOBS;                 // 256 KB
    float* epsum = (float*)(epA_lo + NY * NOBS);                 // 1 f32

    hipMemsetAsync(epsum, 0, sizeof(float), stream);
    prep_kernel<<<NOBS / 4, 256, 0, stream>>>(X, Y, W, b, yhat, epsum,
                                              epT_hi, epT_lo, epA_hi, epA_md, epA_lo);
    solve_kernel<<<NOBS / BS, NT, 0, stream>>>(yhat, epsum, rho,
                                               epT_hi, epT_lo, epA_hi, epA_md, epA_lo, zout);
}

// Round 12
// 2380.636 us; speedup vs baseline: 1.3802x; 1.0398x over previous
//
#include <hip/hip_runtime.h>

#define NOBS 2048
#define NX   128
#define NY   64
#define BS   8            // scenarios per solver block (256 blocks, 1/CU, all resident)
#define NT   1024         // 16 waves
#define NWAVE (NT / 64)
#define NITER 64

typedef short short8 __attribute__((ext_vector_type(8)));   // 8 bf16 (4 VGPRs)
typedef float f32x4 __attribute__((ext_vector_type(4)));    // MFMA accumulator
typedef unsigned short u16x4 __attribute__((ext_vector_type(4)));

// ---- bf16 split helpers (RNE) ----
__device__ __forceinline__ unsigned short bf16_rne(float x) {
    unsigned u = __float_as_uint(x);
    return (unsigned short)((u + 0x7FFFu + ((u >> 16) & 1u)) >> 16);
}
__device__ __forceinline__ float bf16_tof(unsigned short h) {
    return __uint_as_float(((unsigned)h) << 16);
}

// ---- DPP wave reduction (prep only) ----
template <int CTRL>
__device__ __forceinline__ float dpp_f(float x) {
    return __int_as_float(__builtin_amdgcn_update_dpp(
        0, __float_as_int(x), CTRL, 0xf, 0xf, true));
}
__device__ __forceinline__ float wave_sum64(float v) {
    v += dpp_f<0x111>(v);
    v += dpp_f<0x112>(v);
    v += dpp_f<0x114>(v);
    v += dpp_f<0x118>(v);
    v += dpp_f<0x142>(v);
    v += dpp_f<0x143>(v);   // lane 63 = total
    return v;
}

// ---- Kernel 1: Y_hat = X@W^T + b ; epsum ; ep bf16 3-way split, PACKED frags ----
// e = hi + md + lo + r, |r| <~ 2^-24 |e|.
// epT_pack[frag][16]: hi(8) | md(8)      (Phase C A-operand, rows=k, K=i)
// epA_pack[frag][24]: hi(8) | md(8) | lo(8)  (Phase A A-operand, rows=i, K=k)
// Packing puts all split planes of one fragment behind ONE address register
// (offset:16/32 immediates) — kills ~10 addressing VGPRs in the solve loop.
__global__ __launch_bounds__(256) void prep_kernel(
    const float* __restrict__ X, const float* __restrict__ Y,
    const float* __restrict__ W, const float* __restrict__ b,
    float* __restrict__ yhat_out, float* __restrict__ epsum,
    unsigned short* __restrict__ epT_pack, unsigned short* __restrict__ epA_pack)
{
    __shared__ float Xs[4][NX];
    const int t = threadIdx.x;
    const int row0 = blockIdx.x * 4;
    for (int f = t; f < 4 * NX; f += 256)
        Xs[f >> 7][f & 127] = X[(row0 + (f >> 7)) * NX + (f & 127)];
    __syncthreads();

    const int k = t & 63;
    const int r = t >> 6;
    const float4* W4 = reinterpret_cast<const float4*>(W + k * NX);
    const float4* X4 = reinterpret_cast<const float4*>(&Xs[r][0]);
    float acc = 0.f;
    #pragma unroll
    for (int x = 0; x < NX / 4; ++x) {
        float4 wv = W4[x];
        float4 xv = X4[x];
        acc += wv.x * xv.x + wv.y * xv.y + wv.z * xv.z + wv.w * xv.w;
    }
    const float yh = acc + b[k];
    const int i = row0 + r;
    yhat_out[i * NY + k] = yh;
    const float e = Y[i * NY + k] - yh;

    const unsigned short hi = bf16_rne(e);
    const float r1 = e - bf16_tof(hi);
    const unsigned short md = bf16_rne(r1);
    const unsigned short lo = bf16_rne(r1 - bf16_tof(md));
    // Phase C frag (rows = k, K = i):  A[row=lane&15][kk=8*(lane>>4)+d]
    {
        const int m  = k >> 4;
        const int q  = i >> 5;
        const int lc = (k & 15) + 16 * ((i >> 3) & 3);
        const int d  = i & 7;
        const int fT = (m * 64 + q) * 64 + lc;
        epT_pack[fT * 16 + d]     = hi;
        epT_pack[fT * 16 + 8 + d] = md;
    }
    // Phase A frag (rows = i, K = k)
    {
        const int m  = i >> 4;
        const int q  = k >> 5;
        const int lc = (i & 15) + 16 * ((k >> 3) & 3);
        const int d  = k & 7;
        const int fA = (m * 2 + q) * 64 + lc;
        epA_pack[fA * 24 + d]      = hi;
        epA_pack[fA * 24 + 8 + d]  = md;
        epA_pack[fA * 24 + 16 + d] = lo;
    }

    float se = wave_sum64(e);
    if ((t & 63) == 63) atomicAdd(epsum, se);
}

// ---- Kernel 2: batched projected-subgradient DRO solve ----
// Phase A on MFMA (3-way split, 6 terms, FOUR passes of 2 m-tiles, acc
// streamed straight to LDS); Phase C on MFMA (2-way, 3 terms). 5 barriers.
// Anti-spill (R7-R11): per-thread budget is ~64 arch VGPRs (+AGPR block);
// demand must fit or scratch traffic (L2-bypassing) dominates. Cuts here:
// acc[2] passes, no sv_ register array (raw acc -> Sbuf, -cR applied at
// use: bit-identical), packed frags (one address set per operand).
__global__ __launch_bounds__(NT)
__attribute__((amdgpu_waves_per_eu(4, 4)))
void solve_kernel(
    const float* __restrict__ yhat, const float* __restrict__ epsum,
    const float* __restrict__ rho_p,
    const unsigned short* __restrict__ epT_pack,
    const unsigned short* __restrict__ epA_pack,
    float* __restrict__ zout)
{
    __shared__ float Zs[BS][NY];                 // 2 KB
    __shared__ float Yh[BS][NY];                 // 2 KB
    __shared__ unsigned short VT_hi[BS][2056];   // 32.1 KB
    __shared__ unsigned short VT_lo[BS][2056];   // 32.1 KB
    __shared__ __align__(16) unsigned short Zb_hi[16][72];  // 2.25 KB (cols 8..15 dup)
    __shared__ __align__(16) unsigned short Zb_md[16][72];  // 2.25 KB
    __shared__ __align__(16) unsigned short Zb_lo[16][72];  // 2.25 KB
    __shared__ float Rp2[4][4][64][4];           // 16 KB  [g][m][lane][reg]
    __shared__ float4 Sbuf[NWAVE][4][64];        // 64 KB  per-thread raw-acc stash
    __shared__ float redM[NWAVE][BS];            // per-wave umax partials
    __shared__ float red2[NWAVE][BS][4];         // per-wave {pa,pe,pas,pes}
    __shared__ float cS[16], lamS[16];           // cols 8..15 dup
    __shared__ __align__(16) unsigned short zb[8];

    const int t = threadIdx.x;
    const int lane = t & 63;
    const int wv = t >> 6;
    const int jb = lane & 15;      // MFMA column
    const int h  = lane >> 4;      // frag k-chunk / row-group
    const int j8 = jb & 7;         // actual scenario
    const bool hiHalf = (jb >= 8);
    const int sc0 = blockIdx.x * BS;
    const float rho = rho_p[0];

    if (t < BS * NY) {
        const int j = t >> 6, k = t & 63;
        Yh[j][k] = yhat[(sc0 + j) * NY + k];
        Zs[j][k] = 1.0f / 64.0f;
    }
    {   // z0 = 1/64 exact in bf16 (power of two) -> md = lo = 0
        const int j = t >> 6, k = t & 63;
        Zb_hi[j][k] = bf16_rne(1.0f / 64.0f);
        Zb_md[j][k] = 0;
        Zb_lo[j][k] = 0;
    }
    if (t < 16) {
        cS[t] = epsum[0] * (1.0f / 131072.0f);  // mean(ep) == mean(ep @ z0)
        lamS[t] = 1.0f;
    }
    if (t < 8) zb[t] = 0;
    __syncthreads();

    for (int it = 0; it < NITER; ++it) {
        const float lr = 0.05f / sqrtf((float)it + 1.0f);

        const float cR = cS[jb];
        const float lm = lamS[jb];

        // ---- Phase A: raw S-partials via MFMA, 6-term 3-way split, 4 passes ----
        // pass p covers m-tiles {2p, 2p+1}; lo-half lanes keep passes 0-1,
        // hi-half keep 2-3. acc goes straight to Sbuf (no register array).
        #pragma unroll
        for (int pass = 0; pass < 4; ++pass) {
            f32x4 acc0 = {0.f, 0.f, 0.f, 0.f};
            f32x4 acc1 = {0.f, 0.f, 0.f, 0.f};
            #pragma unroll
            for (int q = 0; q < 2; ++q) {
                const short8 zh = *(const short8*)&Zb_hi[jb][(q << 5) + (h << 3)];
                const short8 zm = *(const short8*)&Zb_md[jb][(q << 5) + (h << 3)];
                const short8 zl = *(const short8*)&Zb_lo[jb][(q << 5) + (h << 3)];
                #pragma unroll
                for (int kk = 0; kk < 2; ++kk) {
                    const int mi = pass * 2 + kk;
                    const unsigned short* pb = epA_pack
                        + (size_t)((((wv << 3) + mi) * 2 + q) * 64 + lane) * 24;
                    const short8 ah = *(const short8*)(pb);
                    const short8 am = *(const short8*)(pb + 8);
                    const short8 al = *(const short8*)(pb + 16);
                    f32x4 a = kk ? acc1 : acc0;
                    a = __builtin_amdgcn_mfma_f32_16x16x32_bf16(al, zh, a, 0, 0, 0); // lH
                    a = __builtin_amdgcn_mfma_f32_16x16x32_bf16(ah, zl, a, 0, 0, 0); // hL
                    a = __builtin_amdgcn_mfma_f32_16x16x32_bf16(am, zm, a, 0, 0, 0); // mM
                    a = __builtin_amdgcn_mfma_f32_16x16x32_bf16(am, zh, a, 0, 0, 0); // mH
                    a = __builtin_amdgcn_mfma_f32_16x16x32_bf16(ah, zm, a, 0, 0, 0); // hM
                    a = __builtin_amdgcn_mfma_f32_16x16x32_bf16(ah, zh, a, 0, 0, 0); // hH
                    if (kk) acc1 = a; else acc0 = a;
                }
            }
            const bool take = hiHalf ? (pass >= 2) : (pass < 2);
            if (take) {
                const int nb = (pass & 1) * 2;   // n = 0/1 or 2/3
                Sbuf[wv][nb + 0][lane] = make_float4(acc0[0], acc0[1], acc0[2], acc0[3]);
                Sbuf[wv][nb + 1][lane] = make_float4(acc1[0], acc1[1], acc1[2], acc1[3]);
            }
            __builtin_amdgcn_sched_barrier(0);   // keep passes separate (cap liveness)
        }

        // ---- Phase B1: per-wave umax (read Sbuf, s = acc - cR; u = s*s) ----
        float pm = 0.f;
        #pragma unroll
        for (int n = 0; n < 4; ++n) {
            const float4 s4 = Sbuf[wv][n][lane];
            const float sarr[4] = {s4.x, s4.y, s4.z, s4.w};
            #pragma unroll
            for (int p = 0; p < 4; ++p) {
                const float ss = sarr[p] - cR;
                pm = fmaxf(pm, ss * ss);
            }
        }
        pm = fmaxf(pm, __shfl_xor(pm, 8, 64));
        pm = fmaxf(pm, __shfl_xor(pm, 16, 64));
        pm = fmaxf(pm, __shfl_xor(pm, 32, 64));
        if (lane < 8) redM[wv][lane] = pm;
        __syncthreads();   // bar 1

        // ---- umax fold (all lanes) ----
        float um = redM[0][j8];
        #pragma unroll
        for (int w = 1; w < NWAVE; ++w) um = fmaxf(um, redM[w][j8]);

        // ---- Phase B2: sums of a, eq, a*s, eq*s (JAX balanced-tie semantics) ----
        float pa = 0.f, pe = 0.f, pas = 0.f, pes = 0.f;
        #pragma unroll
        for (int n = 0; n < 4; ++n) {
            const float4 s4 = Sbuf[wv][n][lane];
            const float sarr[4] = {s4.x, s4.y, s4.z, s4.w};
            #pragma unroll
            for (int p = 0; p < 4; ++p) {
                const float ss = sarr[p] - cR, u = ss * ss;
                const float x = (u - um) + lm;
                const float a = (x > -lm) ? 1.0f : ((x == -lm) ? 0.5f : 0.0f);
                const float e = (u == um) ? 1.0f : 0.0f;
                pa += a; pe += e; pas += a * ss; pes += e * ss;
            }
        }
        pa  += __shfl_xor(pa, 8, 64);  pa  += __shfl_xor(pa, 16, 64);  pa  += __shfl_xor(pa, 32, 64);
        pe  += __shfl_xor(pe, 8, 64);  pe  += __shfl_xor(pe, 16, 64);  pe  += __shfl_xor(pe, 32, 64);
        pas += __shfl_xor(pas, 8, 64); pas += __shfl_xor(pas, 16, 64); pas += __shfl_xor(pas, 32, 64);
        pes += __shfl_xor(pes, 8, 64); pes += __shfl_xor(pes, 16, 64); pes += __shfl_xor(pes, 32, 64);
        if (lane < 8) {
            f32x4 r4 = {pa, pe, pas, pes};
            *(f32x4*)&red2[wv][lane][0] = r4;
        }
        __syncthreads();   // bar 2

        // ---- sum fold (all lanes, b128 broadcast reads); c/lam update by wave 0 ----
        float sA = 0.f, sE = 0.f, sAS = 0.f, sES = 0.f;
        #pragma unroll
        for (int w = 0; w < NWAVE; ++w) {
            const f32x4 rr = *(const f32x4*)&red2[w][j8][0];
            sA += rr[0]; sE += rr[1]; sAS += rr[2]; sES += rr[3];
        }
        const float abar = sA * (1.0f / (float)NOBS);
        const float wA = (1.0f - abar) / sE;      // argmax weight / tie count
        const float gc = -2.0f * (sAS * (1.0f / (float)NOBS) + wA * sES);
        const float glam = (rho - 2.0f) + 2.0f * abar;
        if (wv == 0 && lane < 16) {               // consumed next iteration (after bar 5)
            cS[lane] = cS[lane] - lr * gc;
            lamS[lane] = fmaxf(lamS[lane] - lr * glam, 0.0f);
        }

        // ---- Phase B4: v = (a/n + eq*wA) * s -> bf16 hi/lo packed b64 into VT ----
        #pragma unroll
        for (int n = 0; n < 4; ++n) {
            const float4 s4 = Sbuf[wv][n][lane];
            const float sarr[4] = {s4.x, s4.y, s4.z, s4.w};
            u16x4 vh4, vl4;
            #pragma unroll
            for (int p = 0; p < 4; ++p) {
                const float ss = sarr[p] - cR, u = ss * ss;
                const float x = (u - um) + lm;
                const float a = (x > -lm) ? 1.0f : ((x == -lm) ? 0.5f : 0.0f);
                const float e = (u == um) ? 1.0f : 0.0f;
                const float vv = (a * (1.0f / (float)NOBS) + e * wA) * ss;
                const unsigned short vhh = bf16_rne(vv);
                vh4[p] = vhh;
                vl4[p] = bf16_rne(vv - bf16_tof(vhh));
            }
            const int ii = ((wv << 3) + (hiHalf ? 4 : 0) + n) * 16 + (h << 2);
            *(u16x4*)&VT_hi[j8][ii] = vh4;
            *(u16x4*)&VT_lo[j8][ii] = vl4;
        }
        __syncthreads();   // bar 3

        // ---- Phase C: r = ep^T v via MFMA, 3-term 2-way split (R5-proven) ----
        {
            const int m = wv & 3;
            const int g = wv >> 2;
            f32x4 accC = {0.f, 0.f, 0.f, 0.f};
            #pragma unroll 4
            for (int qq = 0; qq < 16; ++qq) {
                const int q = g * 16 + qq;
                const unsigned short* pb = epT_pack
                    + (size_t)((m * 64 + q) * 64 + lane) * 16;
                const short8 ah = *(const short8*)(pb);
                const short8 al = *(const short8*)(pb + 8);
                const unsigned short* vh = (!hiHalf) ? &VT_hi[jb][(q << 5) + (h << 3)] : zb;
                const unsigned short* vl = (!hiHalf) ? &VT_lo[jb][(q << 5) + (h << 3)] : zb;
                const short8 bh = *(const short8*)vh;
                const short8 bl = *(const short8*)vl;
                accC = __builtin_amdgcn_mfma_f32_16x16x32_bf16(al, bh, accC, 0, 0, 0);
                accC = __builtin_amdgcn_mfma_f32_16x16x32_bf16(ah, bl, accC, 0, 0, 0);
                accC = __builtin_amdgcn_mfma_f32_16x16x32_bf16(ah, bh, accC, 0, 0, 0);
            }
            *(f32x4*)(&Rp2[g][m][lane][0]) = accC;
        }
        __syncthreads();   // bar 4

        // ---- Phase D: fold Rp2; update + simplex projection (wave j); z -> 3-way split ----
        if (wv < BS) {
            const int j = wv, k = lane;
            const int m = k >> 4, p = k & 3, ll = ((k >> 2) & 3) * 16 + j;
            const float r = Rp2[0][m][ll][p] + Rp2[1][m][ll][p]
                          + Rp2[2][m][ll][p] + Rp2[3][m][ll][p];
            const float gz = 2.0f * r - Yh[j][k];
            const float vz = Zs[j][k] - lr * gz;

            // bitonic sort (descending) across 64 lanes
            float sv2 = vz;
            #pragma unroll
            for (int sz = 2; sz <= 64; sz <<= 1) {
                #pragma unroll
                for (int st = sz >> 1; st > 0; st >>= 1) {
                    const float other = __shfl_xor(sv2, st, 64);
                    const bool desc = ((lane & sz) == 0);
                    const bool lower = ((lane & st) == 0);
                    const float mx = fmaxf(sv2, other), mn = fminf(sv2, other);
                    sv2 = (lower == desc) ? mx : mn;
                }
            }
            // inclusive scan -> cumsum - 1
            float css = sv2;
            #pragma unroll
            for (int off = 1; off < 64; off <<= 1) {
                const float nb = __shfl_up(css, off, 64);
                if (lane >= off) css += nb;
            }
            css -= 1.0f;
            const bool cond = (sv2 - css / (float)(lane + 1)) > 0.0f;
            const unsigned long long bal = __ballot(cond);
            const int idx = __popcll(bal) - 1;
            const float cssIdx = __shfl(css, idx, 64);
            const float theta = cssIdx / (float)(idx + 1);
            const float zk = fmaxf(vz - theta, 0.0f);
            Zs[j][k] = zk;
            const unsigned short zh_ = bf16_rne(zk);
            const float zr1 = zk - bf16_tof(zh_);
            const unsigned short zm_ = bf16_rne(zr1);
            const unsigned short zl_ = bf16_rne(zr1 - bf16_tof(zm_));
            Zb_hi[j][k] = zh_; Zb_hi[j + 8][k] = zh_;   // duplicate into cols 8..15
            Zb_md[j][k] = zm_; Zb_md[j + 8][k] = zm_;
            Zb_lo[j][k] = zl_; Zb_lo[j + 8][k] = zl_;
        }
        __syncthreads();   // bar 5
    }

    if (t < BS * NY) {
        const int j = t >> 6, k = t & 63;
        zout[(sc0 + j) * NY + k] = Zs[j][k];
    }
}

extern "C" void kernel_launch(void* const* d_in, const int* in_sizes, int n_in,
                              void* d_out, int out_size, void* d_ws, size_t ws_size,
                              hipStream_t stream) {
    const float* X   = (const float*)d_in[0];
    const float* Y   = (const float*)d_in[1];
    const float* rho = (const float*)d_in[2];
    const float* W   = (const float*)d_in[3];
    const float* b   = (const float*)d_in[4];

    float* out   = (float*)d_out;
    float* zout  = out;                 // Z_star: 2048*64
    float* yhat  = out + NOBS * NY;     // Y_hat:  2048*64

    // workspace: epT_pack (512 KB) | epA_pack (768 KB) | epsum (4 B)
    unsigned short* epT_pack = (unsigned short*)d_ws;            // 2048*64*2 shorts
    unsigned short* epA_pack = epT_pack + NY * NOBS * 2;         // 2048*64*3 shorts
    float* epsum = (float*)(epA_pack + NY * NOBS * 3);           // 1 f32

    hipMemsetAsync(epsum, 0, sizeof(float), stream);
    prep_kernel<<<NOBS / 4, 256, 0, stream>>>(X, Y, W, b, yhat, epsum,
                                              epT_pack, epA_pack);
    solve_kernel<<<NOBS / BS, NT, 0, stream>>>(yhat, epsum, rho,
                                               epT_pack, epA_pack, zout);
}